// Round 10
// baseline (660.756 us; speedup 1.0000x reference)
//
#include <hip/hip_runtime.h>

#define SPATIAL 16384
#define BATCH 8
#define CDIM 384
#define QVDIM 768
#define PDIM 192
#define NHEADS 8
#define HC 48

typedef __attribute__((ext_vector_type(8))) short short8;
typedef __attribute__((ext_vector_type(4))) float f32x4;
typedef __attribute__((ext_vector_type(4))) int i32x4;

__device__ __forceinline__ unsigned short f2bf(float f) {
  union { float f; unsigned u; } v; v.f = f;
  unsigned r = v.u + 0x7fffu + ((v.u >> 16) & 1u);
  return (unsigned short)(r >> 16);
}
__device__ __forceinline__ float bf2f(unsigned short h) {
  union { unsigned u; float f; } v; v.u = ((unsigned)h) << 16;
  return v.f;
}

// async global->LDS, 16B per lane; LDS dest is wave-uniform base + lane*16
__device__ __forceinline__ void gload16(const unsigned short* g, unsigned short* lds) {
  __builtin_amdgcn_global_load_lds(
      (const __attribute__((address_space(1))) void*)g,
      (__attribute__((address_space(3))) void*)lds,
      16, 0, 0);
}

// ---------------- weight fp32 -> bf16 ----------------
__global__ void k_w2bf(const float* __restrict__ in, unsigned short* __restrict__ out, int n) {
  int i = blockIdx.x * 256 + threadIdx.x;
  if (i < n) out[i] = f2bf(in[i]);
}

// ---------------- transpose fp32 [B][C][S] -> bf16 [B][S][C], 64x64 tiles ----------------
__global__ __launch_bounds__(256)
void k_transpose(const float* __restrict__ in, unsigned short* __restrict__ out, int C) {
  __shared__ float tile[64][65];
  int bid = blockIdx.x;
  int st = bid % (SPATIAL / 64); bid /= (SPATIAL / 64);
  int ct = bid % (C / 64); int b = bid / (C / 64);
  int t = threadIdx.x;
  const float* ip = in + ((size_t)b * C + (size_t)ct * 64) * SPATIAL + (size_t)st * 64;
  int fx = t & 15, fy = t >> 4;
#pragma unroll
  for (int i = 0; i < 4; i++) {
    int r = fy + i * 16;
    f32x4 v = *(const f32x4*)(ip + (size_t)r * SPATIAL + fx * 4);
    tile[r][fx * 4 + 0] = v[0];
    tile[r][fx * 4 + 1] = v[1];
    tile[r][fx * 4 + 2] = v[2];
    tile[r][fx * 4 + 3] = v[3];
  }
  __syncthreads();
  unsigned short* op = out + ((size_t)b * SPATIAL + (size_t)st * 64) * C + (size_t)ct * 64;
  int cg = t & 7, sr = t >> 3;
#pragma unroll
  for (int i = 0; i < 2; i++) {
    int s = sr + i * 32;
    short8 o;
#pragma unroll
    for (int j = 0; j < 8; j++) o[j] = (short)f2bf(tile[cg * 8 + j][s]);
    *(short8*)(op + (size_t)s * C + cg * 8) = o;
  }
}

// ---------------- GEMM: C[b][M][S] = A[M][K] @ B[b][S][K]^T ----------------
// Phased schedule on the r8 staging protocol.
//   tile top: counted vmcnt(SL)  ->  s_barrier   (PUBLISH: every wave's chunks
//             of tile j are in LDS before anyone reads — the r9 race fix)
//   body: MFR/2 phases; phase p = { ds_reads (p==0: 8 B + 4 A, else 4 A)
//         -> s_barrier -> lgkmcnt(0) -> setprio(1) + 16 MFMA + setprio(0)
//         -> s_barrier }   (one wave's reads overlap other waves' MFMA)
//   tile end: STAGE(j+2) into the buffer just drained (fenced by the trailing
//             phase barrier; vmcnt never drains mid-loop).
// Per-cell accumulate order (h0 then h1) identical to r8 -> bit-identical C.
template<int BM, bool OUT_BF16>
__global__ __launch_bounds__(512, 2)
void k_gemm(const unsigned short* __restrict__ A, const unsigned short* __restrict__ B,
            void* __restrict__ Cv, int M, int K, long strideA)
{
  constexpr int MFR = BM / 32;          // m-frags per wave (8 or 4)
  constexpr int ARD = BM / 64;          // A staging rounds (4 or 2)
  constexpr int SL  = ARD + 4;          // stage loads per thread per K-tile
  constexpr int ASZ = BM * 64;          // A-tile elems
  constexpr int BUF = ASZ + 256 * 64;   // elems per buffer
  constexpr int NPH = MFR / 2;          // phases per K-tile (4 or 2)

  int nwg = gridDim.x;                  // % 8 == 0
  int bid = (blockIdx.x & 7) * (nwg >> 3) + (blockIdx.x >> 3);
  int mt = M / BM;
  int mb = bid % mt; bid /= mt;
  int nb = bid & 63; int b = bid >> 6;

  const unsigned short* Ab = A + (size_t)b * strideA + (size_t)mb * BM * K;
  const unsigned short* Bb = B + ((size_t)b * SPATIAL + (size_t)nb * 256) * K;

  __shared__ unsigned short lds[2 * BUF];

  int t = threadIdx.x;
  int lane = t & 63;
  int w = t >> 6;
  int wm = (w >> 2) * (BM / 2), wn = (w & 3) * 64;
  int lr = lane & 15, lg = lane >> 4;

  f32x4 acc[MFR][4];
#pragma unroll
  for (int i = 0; i < MFR; i++)
#pragma unroll
    for (int j = 0; j < 4; j++)
      acc[i][j] = (f32x4){0.f, 0.f, 0.f, 0.f};

  // staging: thread t -> row (t>>3) per 64-row round, k-slot (t&7)^(row&7)
  int arow = t >> 3;
  int aslot = (t & 7) ^ (arow & 7);
  const unsigned short* gA0 = Ab + (size_t)arow * K + aslot * 8;
  const unsigned short* gB0 = Bb + (size_t)arow * K + aslot * 8;

  auto STAGE = [&](int kt, int q) {
    int k0 = kt * 64;
    unsigned short* base = &lds[q * BUF];
#pragma unroll
    for (int r = 0; r < ARD; ++r)
      gload16(gA0 + (size_t)r * 64 * K + k0, base + r * 4096 + w * 512);
#pragma unroll
    for (int r = 0; r < 4; ++r)
      gload16(gB0 + (size_t)r * 64 * K + k0, base + ASZ + r * 4096 + w * 512);
  };

  int nt = K >> 6;                      // 6 or 3
  STAGE(0, 0);
  STAGE(1, 1);

  // fragment read slot per k-half (xor term is lr&7 for every frag row)
  int colr0 = ((0 * 4 + lg) ^ (lr & 7)) * 8;
  int colr1 = ((1 * 4 + lg) ^ (lr & 7)) * 8;

  for (int j = 0; j < nt; ++j) {
    if (j + 1 < nt) { asm volatile("s_waitcnt vmcnt(%0)" :: "n"(SL) : "memory"); }
    else            { asm volatile("s_waitcnt vmcnt(0)" ::: "memory"); }
    __builtin_amdgcn_s_barrier();        // PUBLISH tile j across waves (r9 fix)
    __builtin_amdgcn_sched_barrier(0);

    unsigned short* cb = &lds[(j & 1) * BUF];

    short8 bfv[4][2];                    // all B frags, both halves (read in phase 0)
#pragma unroll
    for (int p = 0; p < NPH; ++p) {
      if (p == 0) {
#pragma unroll
        for (int ni = 0; ni < 4; ++ni) {
          bfv[ni][0] = *(const short8*)(&cb[ASZ + (wn + ni * 16 + lr) * 64 + colr0]);
          bfv[ni][1] = *(const short8*)(&cb[ASZ + (wn + ni * 16 + lr) * 64 + colr1]);
        }
      }
      short8 af[2][2];
#pragma unroll
      for (int m2 = 0; m2 < 2; ++m2) {
        int row = wm + (2 * p + m2) * 16 + lr;
        af[m2][0] = *(const short8*)(&cb[row * 64 + colr0]);
        af[m2][1] = *(const short8*)(&cb[row * 64 + colr1]);
      }
      __builtin_amdgcn_s_barrier();
      asm volatile("s_waitcnt lgkmcnt(0)" ::: "memory");
      __builtin_amdgcn_sched_barrier(0);
      __builtin_amdgcn_s_setprio(1);
#pragma unroll
      for (int m2 = 0; m2 < 2; ++m2)
#pragma unroll
        for (int ni = 0; ni < 4; ++ni) {
          acc[2 * p + m2][ni] = __builtin_amdgcn_mfma_f32_16x16x32_bf16(
              af[m2][0], bfv[ni][0], acc[2 * p + m2][ni], 0, 0, 0);
          acc[2 * p + m2][ni] = __builtin_amdgcn_mfma_f32_16x16x32_bf16(
              af[m2][1], bfv[ni][1], acc[2 * p + m2][ni], 0, 0, 0);
        }
      __builtin_amdgcn_s_setprio(0);
      __builtin_amdgcn_sched_barrier(0);
      __builtin_amdgcn_s_barrier();
    }
    if (j + 2 < nt) STAGE(j + 2, j & 1);
  }

  size_t rbase = (size_t)mb * BM + wm + lg * 4;
  size_t cbase = (size_t)nb * 256 + wn + lr;
  if (OUT_BF16) {
    unsigned short* C = (unsigned short*)Cv + (size_t)b * M * SPATIAL;
#pragma unroll
    for (int mi = 0; mi < MFR; ++mi)
#pragma unroll
      for (int ni = 0; ni < 4; ++ni) {
        size_t r = rbase + mi * 16;
        size_t c = cbase + ni * 16;
#pragma unroll
        for (int jj = 0; jj < 4; ++jj)
          C[(r + jj) * SPATIAL + c] = f2bf(acc[mi][ni][jj]);
      }
  } else {
    float* C = (float*)Cv + (size_t)b * M * SPATIAL;
#pragma unroll
    for (int mi = 0; mi < MFR; ++mi)
#pragma unroll
      for (int ni = 0; ni < 4; ++ni) {
        size_t r = rbase + mi * 16;
        size_t c = cbase + ni * 16;
#pragma unroll
        for (int jj = 0; jj < 4; ++jj)
          C[(r + jj) * SPATIAL + c] = acc[mi][ni][jj];
      }
  }
}

// ---------------- depthwise 3x3, vectorized: 8 x-pixels per thread ----------------
template<bool NORM>
__global__ __launch_bounds__(256)
void k_dwconv(const unsigned short* __restrict__ in, const float* __restrict__ wdw,
              unsigned short* __restrict__ out, float* __restrict__ norm2,
              int C, int in_cstride, int chan_off)
{
  int bid = blockIdx.x;
  int yt = bid & 7; bid >>= 3;                        // 8 y-tiles of 16 rows
  int c = bid % C; int b = bid / C;
  const unsigned short* ip = in + ((size_t)b * in_cstride + chan_off + c) * SPATIAL;
  const float* wp = wdw + (size_t)(chan_off + c) * 9;
  float wr[9];
#pragma unroll
  for (int i = 0; i < 9; i++) wr[i] = wp[i];

  int t = threadIdx.x;
  int ty = t >> 4, xs = (t & 15) * 8;
  int y = yt * 16 + ty;

  float acc[8];
#pragma unroll
  for (int j = 0; j < 8; j++) acc[j] = 0.f;

  auto row = [&](int yy, float wa, float wb, float wc) {
    if ((unsigned)yy >= 128u) return;
    const unsigned short* rp = ip + yy * 128 + xs;
    short8 cv = *(const short8*)rp;
    float cf[8];
#pragma unroll
    for (int j = 0; j < 8; j++) cf[j] = bf2f((unsigned short)cv[j]);
    float lf = (xs > 0) ? bf2f(rp[-1]) : 0.f;
    float rt = (xs < 120) ? bf2f(rp[8]) : 0.f;
    acc[0] += wa * lf + wb * cf[0] + wc * cf[1];
#pragma unroll
    for (int j = 1; j < 7; j++) acc[j] += wa * cf[j - 1] + wb * cf[j] + wc * cf[j + 1];
    acc[7] += wa * cf[6] + wb * cf[7] + wc * rt;
  };
  row(y - 1, wr[0], wr[1], wr[2]);
  row(y,     wr[3], wr[4], wr[5]);
  row(y + 1, wr[6], wr[7], wr[8]);

  short8 o;
  float sq = 0.f;
#pragma unroll
  for (int j = 0; j < 8; j++) {
    o[j] = (short)f2bf(acc[j]);
    if (NORM) { float v = bf2f((unsigned short)o[j]); sq += v * v; }
  }
  *(short8*)(out + ((size_t)b * C + c) * SPATIAL + y * 128 + xs) = o;

  if (NORM) {
#pragma unroll
    for (int off = 32; off > 0; off >>= 1) sq += __shfl_down(sq, off, 64);
    __shared__ float red[4];
    if ((t & 63) == 0) red[t >> 6] = sq;
    __syncthreads();
    if (t == 0)
      atomicAdd(&norm2[(size_t)b * C + c], red[0] + red[1] + red[2] + red[3]);
  }
}

// ---------------- depthwise 3x3 on v-half of qv, vectorized, transposed out vT [B][S][384] ----------------
__global__ __launch_bounds__(256)
void k_dwconv_t(const unsigned short* __restrict__ qv, const float* __restrict__ wdw,
                unsigned short* __restrict__ vT)
{
  __shared__ float tile[128][17];                     // [x][c-local]
  int bid = blockIdx.x;
  int y = bid & 127; bid >>= 7;
  int ct = bid % 24; int b = bid / 24;                // 24 tiles of 16 channels
  int t = threadIdx.x;
  int ci = t >> 4, xs = (t & 15) * 8;
  int c = CDIM + ct * 16 + ci;
  const unsigned short* ip = qv + ((size_t)b * QVDIM + c) * SPATIAL;
  const float* wp = wdw + (size_t)c * 9;
  float wr[9];
#pragma unroll
  for (int i = 0; i < 9; i++) wr[i] = wp[i];

  float acc[8];
#pragma unroll
  for (int j = 0; j < 8; j++) acc[j] = 0.f;

  auto row = [&](int yy, float wa, float wb, float wc) {
    if ((unsigned)yy >= 128u) return;
    const unsigned short* rp = ip + yy * 128 + xs;
    short8 cv = *(const short8*)rp;
    float cf[8];
#pragma unroll
    for (int j = 0; j < 8; j++) cf[j] = bf2f((unsigned short)cv[j]);
    float lf = (xs > 0) ? bf2f(rp[-1]) : 0.f;
    float rt = (xs < 120) ? bf2f(rp[8]) : 0.f;
    acc[0] += wa * lf + wb * cf[0] + wc * cf[1];
#pragma unroll
    for (int j = 1; j < 7; j++) acc[j] += wa * cf[j - 1] + wb * cf[j] + wc * cf[j + 1];
    acc[7] += wa * cf[6] + wb * cf[7] + wc * rt;
  };
  row(y - 1, wr[0], wr[1], wr[2]);
  row(y,     wr[3], wr[4], wr[5]);
  row(y + 1, wr[6], wr[7], wr[8]);

#pragma unroll
  for (int j = 0; j < 8; j++) tile[xs + j][ci] = acc[j];
  __syncthreads();

  int xw = t >> 1, cg = t & 1;
  short8 o;
#pragma unroll
  for (int j = 0; j < 8; j++) o[j] = (short)f2bf(tile[xw][cg * 8 + j]);
  *(short8*)(vT + ((size_t)b * SPATIAL + (size_t)y * 128 + xw) * CDIM + ct * 16 + cg * 8) = o;
}

// ---------------- raw attention logits: raw[b][h][c][d] += sum_s q[c,s]*k[d,s] ----------------
__global__ __launch_bounds__(256)
void k_logits(const unsigned short* __restrict__ qd, const unsigned short* __restrict__ kd,
              float* __restrict__ raw)
{
  int bid = blockIdx.x;
  int sp = bid & 15; bid >>= 4;
  int h = bid & 7; int b = bid >> 3;
  int lane = threadIdx.x & 63, wv = threadIdx.x >> 6;
  int lr = lane & 15, lg = lane >> 4;
  const unsigned short* qp = qd + ((size_t)b * CDIM + h * HC) * SPATIAL;
  const unsigned short* kp = kd + ((size_t)b * CDIM + h * HC) * SPATIAL;
  int s0 = sp * 1024 + wv * 256;
  f32x4 acc[3][3];
#pragma unroll
  for (int i = 0; i < 3; i++)
#pragma unroll
    for (int j = 0; j < 3; j++)
      acc[i][j] = (f32x4){0.f, 0.f, 0.f, 0.f};
  for (int ks = 0; ks < 256; ks += 32) {
    int off = s0 + ks + lg * 8;
    short8 qf[3], kf[3];
#pragma unroll
    for (int i = 0; i < 3; i++) {
      qf[i] = *(const short8*)(qp + (size_t)(i * 16 + lr) * SPATIAL + off);
      kf[i] = *(const short8*)(kp + (size_t)(i * 16 + lr) * SPATIAL + off);
    }
#pragma unroll
    for (int ci = 0; ci < 3; ci++)
#pragma unroll
      for (int di = 0; di < 3; di++)
        acc[ci][di] = __builtin_amdgcn_mfma_f32_16x16x32_bf16(qf[ci], kf[di], acc[ci][di], 0, 0, 0);
  }
  float* rp = raw + ((size_t)(b * NHEADS + h)) * HC * HC;
#pragma unroll
  for (int ci = 0; ci < 3; ci++)
#pragma unroll
    for (int di = 0; di < 3; di++)
#pragma unroll
      for (int j = 0; j < 4; j++)
        atomicAdd(&rp[(ci * 16 + lg * 4 + j) * HC + di * 16 + lr], acc[ci][di][j]);
}

// ---------------- scale by norms+temperature, softmax over d ----------------
__global__ void k_softmax(const float* __restrict__ raw, const float* __restrict__ n2q,
                          const float* __restrict__ n2k, const float* __restrict__ temp,
                          float* __restrict__ attn)
{
  int h = blockIdx.x & 7, b = blockIdx.x >> 3;
  int c = threadIdx.x;
  if (c >= HC) return;
  float tp = temp[h];
  float qn = fmaxf(sqrtf(n2q[b * CDIM + h * HC + c]), 1e-12f);
  const float* rp = raw + ((size_t)(b * NHEADS + h) * HC + c) * HC;
  float vals[HC];
  float mx = -1e30f;
#pragma unroll
  for (int d = 0; d < HC; d++) {
    float kn = fmaxf(sqrtf(n2k[b * CDIM + h * HC + d]), 1e-12f);
    float v = rp[d] * tp / (qn * kn);
    vals[d] = v;
    mx = fmaxf(mx, v);
  }
  float sum = 0.f;
#pragma unroll
  for (int d = 0; d < HC; d++) { vals[d] = expf(vals[d] - mx); sum += vals[d]; }
  float inv = 1.f / sum;
  float* ap = attn + ((size_t)(b * NHEADS + h) * HC + c) * HC;
#pragma unroll
  for (int d = 0; d < HC; d++) ap[d] = vals[d] * inv;
}

// ---------------- M[b][o][h*48+d] = sum_c wproj[o][h*48+c] * attn[b][h][c][d] ----------------
__global__ void k_mbuild(const float* __restrict__ attn, const float* __restrict__ wproj,
                         unsigned short* __restrict__ Mb)
{
  int o = blockIdx.x % CDIM, b = blockIdx.x / CDIM;
  int j = threadIdx.x;           // 0..383
  int h = j / HC, d = j % HC;
  const float* wp = wproj + (size_t)o * CDIM + h * HC;
  const float* ap = attn + (size_t)(b * NHEADS + h) * HC * HC + d;
  float s = 0.f;
#pragma unroll
  for (int cp = 0; cp < HC; cp++) s += wp[cp] * ap[cp * HC];
  Mb[((size_t)b * CDIM + o) * CDIM + j] = f2bf(s);
}

// ---------------- workspace layout (bytes) ----------------
static const size_t OFF_QV   = 0;            // qv bf16 [B][768][S]; later reused as k_dw
static const size_t OFF_KDW  = 0;            // alias: qv fully consumed before this is written
static const size_t OFF_XT   = 201326592;    // xT bf16 [B][S][384]; later q_dw [B][384][S]
static const size_t OFF_QDW  = 201326592;
static const size_t OFF_DET  = 301989888;    // deT bf16 [B][S][192]
static const size_t OFF_VT   = 301989888;    // vT bf16 [B][S][384] (alias over dead deT)
static const size_t OFF_KPRE = 402653184;    // k_pre bf16 [B][384][S]
static const size_t OFF_WQVB = 503316480;
static const size_t OFF_WKB  = 503906304;
static const size_t OFF_N2Q  = 504053760;
static const size_t OFF_N2K  = 504066048;
static const size_t OFF_RAW  = 504078336;
static const size_t OFF_ATTN = 504668160;
static const size_t OFF_MB   = 505257984;    // -> end ~484 MB

extern "C" void kernel_launch(void* const* d_in, const int* in_sizes, int n_in,
                              void* d_out, int out_size, void* d_ws, size_t ws_size,
                              hipStream_t stream) {
  const float* x      = (const float*)d_in[0];
  const float* de     = (const float*)d_in[1];
  const float* w_qv   = (const float*)d_in[2];
  const float* w_qvdw = (const float*)d_in[3];
  const float* w_k    = (const float*)d_in[4];
  const float* w_kdw  = (const float*)d_in[5];
  const float* w_proj = (const float*)d_in[6];
  const float* temp   = (const float*)d_in[7];

  char* ws = (char*)d_ws;
  unsigned short* qv    = (unsigned short*)(ws + OFF_QV);
  unsigned short* kdw   = (unsigned short*)(ws + OFF_KDW);
  unsigned short* xT    = (unsigned short*)(ws + OFF_XT);
  unsigned short* qdw   = (unsigned short*)(ws + OFF_QDW);
  unsigned short* deT   = (unsigned short*)(ws + OFF_DET);
  unsigned short* vT    = (unsigned short*)(ws + OFF_VT);
  unsigned short* kpre  = (unsigned short*)(ws + OFF_KPRE);
  unsigned short* wqvb  = (unsigned short*)(ws + OFF_WQVB);
  unsigned short* wkb   = (unsigned short*)(ws + OFF_WKB);
  float* n2q  = (float*)(ws + OFF_N2Q);
  float* n2k  = (float*)(ws + OFF_N2K);
  float* raw  = (float*)(ws + OFF_RAW);
  float* attn = (float*)(ws + OFF_ATTN);
  unsigned short* Mb = (unsigned short*)(ws + OFF_MB);

  hipMemsetAsync(ws + OFF_N2Q, 0, 12288 + 12288 + 589824, stream);

  k_w2bf<<<dim3((QVDIM * CDIM + 255) / 256), dim3(256), 0, stream>>>(w_qv, wqvb, QVDIM * CDIM);
  k_w2bf<<<dim3((CDIM * PDIM + 255) / 256), dim3(256), 0, stream>>>(w_k, wkb, CDIM * PDIM);

  k_transpose<<<dim3(BATCH * (CDIM / 64) * (SPATIAL / 64)), dim3(256), 0, stream>>>(x, xT, CDIM);
  k_transpose<<<dim3(BATCH * (PDIM / 64) * (SPATIAL / 64)), dim3(256), 0, stream>>>(de, deT, PDIM);

  // GEMM1: qv = w_qv @ x   (M=768, K=384, BM=256, nt=6)
  k_gemm<256, true><<<dim3(BATCH * (QVDIM / 256) * (SPATIAL / 256)), dim3(512), 0, stream>>>(
      wqvb, xT, (void*)qv, QVDIM, CDIM, 0L);
  // GEMM1b: k_pre = w_k @ de (M=384, K=192, BM=128, nt=3)
  k_gemm<128, true><<<dim3(BATCH * (CDIM / 128) * (SPATIAL / 256)), dim3(512), 0, stream>>>(
      wkb, deT, (void*)kpre, CDIM, PDIM, 0L);

  // depthwise convs (vectorized, separate kernels — proven structure)
  k_dwconv<true><<<dim3(BATCH * CDIM * 8), dim3(256), 0, stream>>>(
      qv, w_qvdw, qdw, n2q, CDIM, QVDIM, 0);
  k_dwconv_t<<<dim3(BATCH * 24 * 128), dim3(256), 0, stream>>>(qv, w_qvdw, vT);
  k_dwconv<true><<<dim3(BATCH * CDIM * 8), dim3(256), 0, stream>>>(
      kpre, w_kdw, kdw, n2k, CDIM, CDIM, 0);

  // attention logits, softmax, combined projection matrix
  k_logits<<<dim3(BATCH * NHEADS * 16), dim3(256), 0, stream>>>(qdw, kdw, raw);
  k_softmax<<<dim3(BATCH * NHEADS), dim3(64), 0, stream>>>(raw, n2q, n2k, temp, attn);
  k_mbuild<<<dim3(BATCH * CDIM), dim3(CDIM), 0, stream>>>(attn, w_proj, Mb);

  // GEMM2: out = M[b] @ v  (M=384, K=384, BM=128, nt=6), fp32 output
  k_gemm<128, false><<<dim3(BATCH * (CDIM / 128) * (SPATIAL / 256)), dim3(512), 0, stream>>>(
      Mb, vT, d_out, CDIM, CDIM, (long)(CDIM * CDIM));
}

// Round 11
// 602.547 us; speedup vs baseline: 1.0966x; 1.0966x over previous
//
#include <hip/hip_runtime.h>

#define SPATIAL 16384
#define BATCH 8
#define CDIM 384
#define QVDIM 768
#define PDIM 192
#define NHEADS 8
#define HC 48

typedef __attribute__((ext_vector_type(8))) short short8;
typedef __attribute__((ext_vector_type(4))) float f32x4;
typedef __attribute__((ext_vector_type(4))) int i32x4;

__device__ __forceinline__ unsigned short f2bf(float f) {
  union { float f; unsigned u; } v; v.f = f;
  unsigned r = v.u + 0x7fffu + ((v.u >> 16) & 1u);
  return (unsigned short)(r >> 16);
}
__device__ __forceinline__ float bf2f(unsigned short h) {
  union { unsigned u; float f; } v; v.u = ((unsigned)h) << 16;
  return v.f;
}

// async global->LDS, 16B per lane; LDS dest is wave-uniform base + lane*16
__device__ __forceinline__ void gload16(const unsigned short* g, unsigned short* lds) {
  __builtin_amdgcn_global_load_lds(
      (const __attribute__((address_space(1))) void*)g,
      (__attribute__((address_space(3))) void*)lds,
      16, 0, 0);
}

// ---------------- weight fp32 -> bf16 ----------------
__global__ void k_w2bf(const float* __restrict__ in, unsigned short* __restrict__ out, int n) {
  int i = blockIdx.x * 256 + threadIdx.x;
  if (i < n) out[i] = f2bf(in[i]);
}

// ---------------- transpose fp32 [B][C][S] -> bf16 [B][S][C], 64x64 tiles ----------------
__global__ __launch_bounds__(256)
void k_transpose(const float* __restrict__ in, unsigned short* __restrict__ out, int C) {
  __shared__ float tile[64][65];
  int bid = blockIdx.x;
  int st = bid % (SPATIAL / 64); bid /= (SPATIAL / 64);
  int ct = bid % (C / 64); int b = bid / (C / 64);
  int t = threadIdx.x;
  const float* ip = in + ((size_t)b * C + (size_t)ct * 64) * SPATIAL + (size_t)st * 64;
  int fx = t & 15, fy = t >> 4;
#pragma unroll
  for (int i = 0; i < 4; i++) {
    int r = fy + i * 16;
    f32x4 v = *(const f32x4*)(ip + (size_t)r * SPATIAL + fx * 4);
    tile[r][fx * 4 + 0] = v[0];
    tile[r][fx * 4 + 1] = v[1];
    tile[r][fx * 4 + 2] = v[2];
    tile[r][fx * 4 + 3] = v[3];
  }
  __syncthreads();
  unsigned short* op = out + ((size_t)b * SPATIAL + (size_t)st * 64) * C + (size_t)ct * 64;
  int cg = t & 7, sr = t >> 3;
#pragma unroll
  for (int i = 0; i < 2; i++) {
    int s = sr + i * 32;
    short8 o;
#pragma unroll
    for (int j = 0; j < 8; j++) o[j] = (short)f2bf(tile[cg * 8 + j][s]);
    *(short8*)(op + (size_t)s * C + cg * 8) = o;
  }
}

// ---------------- GEMM: C[b][M][S] = A[M][K] @ B[b][S][K]^T ----------------
// r8 structure (best verified): BK=64 double-buffered, per K-tile one barrier
// pair envelopes 64 MFMA/wave (two k-halves, same frag regs). Stage j+2 after
// the reads-done barrier; counted vmcnt(SL) never drains mid-loop.
template<int BM, bool OUT_BF16>
__global__ __launch_bounds__(512, 2)
void k_gemm(const unsigned short* __restrict__ A, const unsigned short* __restrict__ B,
            void* __restrict__ Cv, int M, int K, long strideA)
{
  constexpr int MFR = BM / 32;          // m-frags per wave (8 or 4)
  constexpr int ARD = BM / 64;          // A staging rounds (4 or 2)
  constexpr int SL  = ARD + 4;          // stage loads per thread per K-tile
  constexpr int ASZ = BM * 64;          // A-tile elems
  constexpr int BUF = ASZ + 256 * 64;   // elems per buffer

  int nwg = gridDim.x;                  // % 8 == 0
  int bid = (blockIdx.x & 7) * (nwg >> 3) + (blockIdx.x >> 3);
  int mt = M / BM;
  int mb = bid % mt; bid /= mt;
  int nb = bid & 63; int b = bid >> 6;

  const unsigned short* Ab = A + (size_t)b * strideA + (size_t)mb * BM * K;
  const unsigned short* Bb = B + ((size_t)b * SPATIAL + (size_t)nb * 256) * K;

  __shared__ unsigned short lds[2 * BUF];

  int t = threadIdx.x;
  int lane = t & 63;
  int w = t >> 6;
  int wm = (w >> 2) * (BM / 2), wn = (w & 3) * 64;
  int lr = lane & 15, lg = lane >> 4;

  f32x4 acc[MFR][4];
#pragma unroll
  for (int i = 0; i < MFR; i++)
#pragma unroll
    for (int j = 0; j < 4; j++)
      acc[i][j] = (f32x4){0.f, 0.f, 0.f, 0.f};

  // staging: thread t -> row (t>>3) per 64-row round, k-slot (t&7)^(row&7)
  int arow = t >> 3;
  int aslot = (t & 7) ^ (arow & 7);
  const unsigned short* gA0 = Ab + (size_t)arow * K + aslot * 8;
  const unsigned short* gB0 = Bb + (size_t)arow * K + aslot * 8;

  auto STAGE = [&](int kt, int q) {
    int k0 = kt * 64;
    unsigned short* base = &lds[q * BUF];
#pragma unroll
    for (int r = 0; r < ARD; ++r)
      gload16(gA0 + (size_t)r * 64 * K + k0, base + r * 4096 + w * 512);
#pragma unroll
    for (int r = 0; r < 4; ++r)
      gload16(gB0 + (size_t)r * 64 * K + k0, base + ASZ + r * 4096 + w * 512);
  };

  int nt = K >> 6;                      // 6 or 3
  STAGE(0, 0);
  STAGE(1, 1);

  // fragment read slot per k-half (xor term is lr&7 for every frag row)
  int colr0 = ((0 * 4 + lg) ^ (lr & 7)) * 8;
  int colr1 = ((1 * 4 + lg) ^ (lr & 7)) * 8;

  for (int j = 0; j < nt; ++j) {
    if (j + 1 < nt) { asm volatile("s_waitcnt vmcnt(%0)" :: "n"(SL) : "memory"); }
    else            { asm volatile("s_waitcnt vmcnt(0)" ::: "memory"); }
    __builtin_amdgcn_s_barrier();            // (a) tile j published
    __builtin_amdgcn_sched_barrier(0);

    unsigned short* cb = &lds[(j & 1) * BUF];

    {  // k-half 0
      short8 af[MFR], bfv[4];
#pragma unroll
      for (int mi = 0; mi < MFR; ++mi)
        af[mi] = *(const short8*)(&cb[(wm + mi * 16 + lr) * 64 + colr0]);
#pragma unroll
      for (int ni = 0; ni < 4; ++ni)
        bfv[ni] = *(const short8*)(&cb[ASZ + (wn + ni * 16 + lr) * 64 + colr0]);
      __builtin_amdgcn_s_setprio(1);
#pragma unroll
      for (int mi = 0; mi < MFR; ++mi)
#pragma unroll
        for (int ni = 0; ni < 4; ++ni)
          acc[mi][ni] = __builtin_amdgcn_mfma_f32_16x16x32_bf16(af[mi], bfv[ni], acc[mi][ni], 0, 0, 0);
      __builtin_amdgcn_s_setprio(0);
    }
    __builtin_amdgcn_sched_barrier(0);       // keep halves separate (reg pressure)
    {  // k-half 1
      short8 af[MFR], bfv[4];
#pragma unroll
      for (int mi = 0; mi < MFR; ++mi)
        af[mi] = *(const short8*)(&cb[(wm + mi * 16 + lr) * 64 + colr1]);
#pragma unroll
      for (int ni = 0; ni < 4; ++ni)
        bfv[ni] = *(const short8*)(&cb[ASZ + (wn + ni * 16 + lr) * 64 + colr1]);
      __builtin_amdgcn_s_setprio(1);
#pragma unroll
      for (int mi = 0; mi < MFR; ++mi)
#pragma unroll
        for (int ni = 0; ni < 4; ++ni)
          acc[mi][ni] = __builtin_amdgcn_mfma_f32_16x16x32_bf16(af[mi], bfv[ni], acc[mi][ni], 0, 0, 0);
      __builtin_amdgcn_s_setprio(0);
    }
    __builtin_amdgcn_sched_barrier(0);
    __builtin_amdgcn_s_barrier();            // (b) all reads done: buffer free
    if (j + 2 < nt) STAGE(j + 2, j & 1);
  }

  size_t rbase = (size_t)mb * BM + wm + lg * 4;
  size_t cbase = (size_t)nb * 256 + wn + lr;
  if (OUT_BF16) {
    unsigned short* C = (unsigned short*)Cv + (size_t)b * M * SPATIAL;
#pragma unroll
    for (int mi = 0; mi < MFR; ++mi)
#pragma unroll
      for (int ni = 0; ni < 4; ++ni) {
        size_t r = rbase + mi * 16;
        size_t c = cbase + ni * 16;
#pragma unroll
        for (int jj = 0; jj < 4; ++jj)
          C[(r + jj) * SPATIAL + c] = f2bf(acc[mi][ni][jj]);
      }
  } else {
    float* C = (float*)Cv + (size_t)b * M * SPATIAL;
#pragma unroll
    for (int mi = 0; mi < MFR; ++mi)
#pragma unroll
      for (int ni = 0; ni < 4; ++ni) {
        size_t r = rbase + mi * 16;
        size_t c = cbase + ni * 16;
#pragma unroll
        for (int jj = 0; jj < 4; ++jj)
          C[(r + jj) * SPATIAL + c] = acc[mi][ni][jj];
      }
  }
}

// ---------------- depthwise 3x3, vectorized, shfl halo: 8 x-pixels per thread ----------------
// Edge pixels come from adjacent lanes' registers (__shfl) instead of scalar
// global loads: 3 loads/thread instead of 9, no x-boundary branches.
template<bool NORM>
__global__ __launch_bounds__(256)
void k_dwconv(const unsigned short* __restrict__ in, const float* __restrict__ wdw,
              unsigned short* __restrict__ out, float* __restrict__ norm2,
              int C, int in_cstride, int chan_off)
{
  int bid = blockIdx.x;
  int yt = bid & 7; bid >>= 3;                        // 8 y-tiles of 16 rows
  int c = bid % C; int b = bid / C;
  const unsigned short* ip = in + ((size_t)b * in_cstride + chan_off + c) * SPATIAL;
  const float* wp = wdw + (size_t)(chan_off + c) * 9;
  float wr[9];
#pragma unroll
  for (int i = 0; i < 9; i++) wr[i] = wp[i];

  int t = threadIdx.x;
  int l = t & 63;                                     // lane
  int g = t & 15;                                     // x-group within row
  int ty = t >> 4, xs = g * 8;
  int y = yt * 16 + ty;

  float acc[8];
#pragma unroll
  for (int j = 0; j < 8; j++) acc[j] = 0.f;

  auto row = [&](int yy, float wa, float wb, float wc) {
    if ((unsigned)yy >= 128u) return;
    const unsigned short* rp = ip + yy * 128 + xs;
    short8 cv = *(const short8*)rp;
    float cf[8];
#pragma unroll
    for (int j = 0; j < 8; j++) cf[j] = bf2f((unsigned short)cv[j]);
    // halo via lane exchange; g==0 / g==15 overridden (SAME padding), which
    // also covers shfl-from-inactive-lane at row-divergence boundaries.
    float lf = __shfl(cf[7], (l - 1) & 63, 64);
    float rt = __shfl(cf[0], (l + 1) & 63, 64);
    if (g == 0)  lf = 0.f;
    if (g == 15) rt = 0.f;
    acc[0] += wa * lf + wb * cf[0] + wc * cf[1];
#pragma unroll
    for (int j = 1; j < 7; j++) acc[j] += wa * cf[j - 1] + wb * cf[j] + wc * cf[j + 1];
    acc[7] += wa * cf[6] + wb * cf[7] + wc * rt;
  };
  row(y - 1, wr[0], wr[1], wr[2]);
  row(y,     wr[3], wr[4], wr[5]);
  row(y + 1, wr[6], wr[7], wr[8]);

  short8 o;
  float sq = 0.f;
#pragma unroll
  for (int j = 0; j < 8; j++) {
    o[j] = (short)f2bf(acc[j]);
    if (NORM) { float v = bf2f((unsigned short)o[j]); sq += v * v; }
  }
  *(short8*)(out + ((size_t)b * C + c) * SPATIAL + y * 128 + xs) = o;

  if (NORM) {
#pragma unroll
    for (int off = 32; off > 0; off >>= 1) sq += __shfl_down(sq, off, 64);
    __shared__ float red[4];
    if ((t & 63) == 0) red[t >> 6] = sq;
    __syncthreads();
    if (t == 0)
      atomicAdd(&norm2[(size_t)b * C + c], red[0] + red[1] + red[2] + red[3]);
  }
}

// ---------------- depthwise 3x3 on v-half of qv, shfl halo, transposed out vT ----------------
__global__ __launch_bounds__(256)
void k_dwconv_t(const unsigned short* __restrict__ qv, const float* __restrict__ wdw,
                unsigned short* __restrict__ vT)
{
  __shared__ float tile[128][17];                     // [x][c-local]
  int bid = blockIdx.x;
  int y = bid & 127; bid >>= 7;
  int ct = bid % 24; int b = bid / 24;                // 24 tiles of 16 channels
  int t = threadIdx.x;
  int l = t & 63;
  int g = t & 15;
  int ci = t >> 4, xs = g * 8;
  int c = CDIM + ct * 16 + ci;
  const unsigned short* ip = qv + ((size_t)b * QVDIM + c) * SPATIAL;
  const float* wp = wdw + (size_t)c * 9;
  float wr[9];
#pragma unroll
  for (int i = 0; i < 9; i++) wr[i] = wp[i];

  float acc[8];
#pragma unroll
  for (int j = 0; j < 8; j++) acc[j] = 0.f;

  auto row = [&](int yy, float wa, float wb, float wc) {
    if ((unsigned)yy >= 128u) return;                 // y uniform per block: no divergence
    const unsigned short* rp = ip + yy * 128 + xs;
    short8 cv = *(const short8*)rp;
    float cf[8];
#pragma unroll
    for (int j = 0; j < 8; j++) cf[j] = bf2f((unsigned short)cv[j]);
    float lf = __shfl(cf[7], (l - 1) & 63, 64);
    float rt = __shfl(cf[0], (l + 1) & 63, 64);
    if (g == 0)  lf = 0.f;
    if (g == 15) rt = 0.f;
    acc[0] += wa * lf + wb * cf[0] + wc * cf[1];
#pragma unroll
    for (int j = 1; j < 7; j++) acc[j] += wa * cf[j - 1] + wb * cf[j] + wc * cf[j + 1];
    acc[7] += wa * cf[6] + wb * cf[7] + wc * rt;
  };
  row(y - 1, wr[0], wr[1], wr[2]);
  row(y,     wr[3], wr[4], wr[5]);
  row(y + 1, wr[6], wr[7], wr[8]);

#pragma unroll
  for (int j = 0; j < 8; j++) tile[xs + j][ci] = acc[j];
  __syncthreads();

  int xw = t >> 1, cg = t & 1;
  short8 o;
#pragma unroll
  for (int j = 0; j < 8; j++) o[j] = (short)f2bf(tile[xw][cg * 8 + j]);
  *(short8*)(vT + ((size_t)b * SPATIAL + (size_t)y * 128 + xw) * CDIM + ct * 16 + cg * 8) = o;
}

// ---------------- raw attention logits: raw[b][h][c][d] += sum_s q[c,s]*k[d,s] ----------------
__global__ __launch_bounds__(256)
void k_logits(const unsigned short* __restrict__ qd, const unsigned short* __restrict__ kd,
              float* __restrict__ raw)
{
  int bid = blockIdx.x;
  int sp = bid & 15; bid >>= 4;
  int h = bid & 7; int b = bid >> 3;
  int lane = threadIdx.x & 63, wv = threadIdx.x >> 6;
  int lr = lane & 15, lg = lane >> 4;
  const unsigned short* qp = qd + ((size_t)b * CDIM + h * HC) * SPATIAL;
  const unsigned short* kp = kd + ((size_t)b * CDIM + h * HC) * SPATIAL;
  int s0 = sp * 1024 + wv * 256;
  f32x4 acc[3][3];
#pragma unroll
  for (int i = 0; i < 3; i++)
#pragma unroll
    for (int j = 0; j < 3; j++)
      acc[i][j] = (f32x4){0.f, 0.f, 0.f, 0.f};
  for (int ks = 0; ks < 256; ks += 32) {
    int off = s0 + ks + lg * 8;
    short8 qf[3], kf[3];
#pragma unroll
    for (int i = 0; i < 3; i++) {
      qf[i] = *(const short8*)(qp + (size_t)(i * 16 + lr) * SPATIAL + off);
      kf[i] = *(const short8*)(kp + (size_t)(i * 16 + lr) * SPATIAL + off);
    }
#pragma unroll
    for (int ci = 0; ci < 3; ci++)
#pragma unroll
      for (int di = 0; di < 3; di++)
        acc[ci][di] = __builtin_amdgcn_mfma_f32_16x16x32_bf16(qf[ci], kf[di], acc[ci][di], 0, 0, 0);
  }
  float* rp = raw + ((size_t)(b * NHEADS + h)) * HC * HC;
#pragma unroll
  for (int ci = 0; ci < 3; ci++)
#pragma unroll
    for (int di = 0; di < 3; di++)
#pragma unroll
      for (int j = 0; j < 4; j++)
        atomicAdd(&rp[(ci * 16 + lg * 4 + j) * HC + di * 16 + lr], acc[ci][di][j]);
}

// ---------------- scale by norms+temperature, softmax over d ----------------
__global__ void k_softmax(const float* __restrict__ raw, const float* __restrict__ n2q,
                          const float* __restrict__ n2k, const float* __restrict__ temp,
                          float* __restrict__ attn)
{
  int h = blockIdx.x & 7, b = blockIdx.x >> 3;
  int c = threadIdx.x;
  if (c >= HC) return;
  float tp = temp[h];
  float qn = fmaxf(sqrtf(n2q[b * CDIM + h * HC + c]), 1e-12f);
  const float* rp = raw + ((size_t)(b * NHEADS + h) * HC + c) * HC;
  float vals[HC];
  float mx = -1e30f;
#pragma unroll
  for (int d = 0; d < HC; d++) {
    float kn = fmaxf(sqrtf(n2k[b * CDIM + h * HC + d]), 1e-12f);
    float v = rp[d] * tp / (qn * kn);
    vals[d] = v;
    mx = fmaxf(mx, v);
  }
  float sum = 0.f;
#pragma unroll
  for (int d = 0; d < HC; d++) { vals[d] = expf(vals[d] - mx); sum += vals[d]; }
  float inv = 1.f / sum;
  float* ap = attn + ((size_t)(b * NHEADS + h) * HC + c) * HC;
#pragma unroll
  for (int d = 0; d < HC; d++) ap[d] = vals[d] * inv;
}

// ---------------- M[b][o][h*48+d] = sum_c wproj[o][h*48+c] * attn[b][h][c][d] ----------------
__global__ void k_mbuild(const float* __restrict__ attn, const float* __restrict__ wproj,
                         unsigned short* __restrict__ Mb)
{
  int o = blockIdx.x % CDIM, b = blockIdx.x / CDIM;
  int j = threadIdx.x;           // 0..383
  int h = j / HC, d = j % HC;
  const float* wp = wproj + (size_t)o * CDIM + h * HC;
  const float* ap = attn + (size_t)(b * NHEADS + h) * HC * HC + d;
  float s = 0.f;
#pragma unroll
  for (int cp = 0; cp < HC; cp++) s += wp[cp] * ap[cp * HC];
  Mb[((size_t)b * CDIM + o) * CDIM + j] = f2bf(s);
}

// ---------------- workspace layout (bytes) ----------------
static const size_t OFF_QV   = 0;            // qv bf16 [B][768][S]; later reused as k_dw
static const size_t OFF_KDW  = 0;            // alias: qv fully consumed before this is written
static const size_t OFF_XT   = 201326592;    // xT bf16 [B][S][384]; later q_dw [B][384][S]
static const size_t OFF_QDW  = 201326592;
static const size_t OFF_DET  = 301989888;    // deT bf16 [B][S][192]
static const size_t OFF_VT   = 301989888;    // vT bf16 [B][S][384] (alias over dead deT)
static const size_t OFF_KPRE = 402653184;    // k_pre bf16 [B][384][S]
static const size_t OFF_WQVB = 503316480;
static const size_t OFF_WKB  = 503906304;
static const size_t OFF_N2Q  = 504053760;
static const size_t OFF_N2K  = 504066048;
static const size_t OFF_RAW  = 504078336;
static const size_t OFF_ATTN = 504668160;
static const size_t OFF_MB   = 505257984;    // -> end ~484 MB

extern "C" void kernel_launch(void* const* d_in, const int* in_sizes, int n_in,
                              void* d_out, int out_size, void* d_ws, size_t ws_size,
                              hipStream_t stream) {
  const float* x      = (const float*)d_in[0];
  const float* de     = (const float*)d_in[1];
  const float* w_qv   = (const float*)d_in[2];
  const float* w_qvdw = (const float*)d_in[3];
  const float* w_k    = (const float*)d_in[4];
  const float* w_kdw  = (const float*)d_in[5];
  const float* w_proj = (const float*)d_in[6];
  const float* temp   = (const float*)d_in[7];

  char* ws = (char*)d_ws;
  unsigned short* qv    = (unsigned short*)(ws + OFF_QV);
  unsigned short* kdw   = (unsigned short*)(ws + OFF_KDW);
  unsigned short* xT    = (unsigned short*)(ws + OFF_XT);
  unsigned short* qdw   = (unsigned short*)(ws + OFF_QDW);
  unsigned short* deT   = (unsigned short*)(ws + OFF_DET);
  unsigned short* vT    = (unsigned short*)(ws + OFF_VT);
  unsigned short* kpre  = (unsigned short*)(ws + OFF_KPRE);
  unsigned short* wqvb  = (unsigned short*)(ws + OFF_WQVB);
  unsigned short* wkb   = (unsigned short*)(ws + OFF_WKB);
  float* n2q  = (float*)(ws + OFF_N2Q);
  float* n2k  = (float*)(ws + OFF_N2K);
  float* raw  = (float*)(ws + OFF_RAW);
  float* attn = (float*)(ws + OFF_ATTN);
  unsigned short* Mb = (unsigned short*)(ws + OFF_MB);

  hipMemsetAsync(ws + OFF_N2Q, 0, 12288 + 12288 + 589824, stream);

  k_w2bf<<<dim3((QVDIM * CDIM + 255) / 256), dim3(256), 0, stream>>>(w_qv, wqvb, QVDIM * CDIM);
  k_w2bf<<<dim3((CDIM * PDIM + 255) / 256), dim3(256), 0, stream>>>(w_k, wkb, CDIM * PDIM);

  k_transpose<<<dim3(BATCH * (CDIM / 64) * (SPATIAL / 64)), dim3(256), 0, stream>>>(x, xT, CDIM);
  k_transpose<<<dim3(BATCH * (PDIM / 64) * (SPATIAL / 64)), dim3(256), 0, stream>>>(de, deT, PDIM);

  // GEMM1: qv = w_qv @ x   (M=768, K=384, BM=256, nt=6)
  k_gemm<256, true><<<dim3(BATCH * (QVDIM / 256) * (SPATIAL / 256)), dim3(512), 0, stream>>>(
      wqvb, xT, (void*)qv, QVDIM, CDIM, 0L);
  // GEMM1b: k_pre = w_k @ de (M=384, K=192, BM=128, nt=3)
  k_gemm<128, true><<<dim3(BATCH * (CDIM / 128) * (SPATIAL / 256)), dim3(512), 0, stream>>>(
      wkb, deT, (void*)kpre, CDIM, PDIM, 0L);

  // depthwise convs (vectorized + shfl halo)
  k_dwconv<true><<<dim3(BATCH * CDIM * 8), dim3(256), 0, stream>>>(
      qv, w_qvdw, qdw, n2q, CDIM, QVDIM, 0);
  k_dwconv_t<<<dim3(BATCH * 24 * 128), dim3(256), 0, stream>>>(qv, w_qvdw, vT);
  k_dwconv<true><<<dim3(BATCH * CDIM * 8), dim3(256), 0, stream>>>(
      kpre, w_kdw, kdw, n2k, CDIM, CDIM, 0);

  // attention logits, softmax, combined projection matrix
  k_logits<<<dim3(BATCH * NHEADS * 16), dim3(256), 0, stream>>>(qdw, kdw, raw);
  k_softmax<<<dim3(BATCH * NHEADS), dim3(64), 0, stream>>>(raw, n2q, n2k, temp, attn);
  k_mbuild<<<dim3(BATCH * CDIM), dim3(CDIM), 0, stream>>>(attn, w_proj, Mb);

  // GEMM2: out = M[b] @ v  (M=384, K=384, BM=128, nt=6), fp32 output
  k_gemm<128, false><<<dim3(BATCH * (CDIM / 128) * (SPATIAL / 256)), dim3(512), 0, stream>>>(
      Mb, vT, d_out, CDIM, CDIM, (long)(CDIM * CDIM));
}

// Round 12
// 579.920 us; speedup vs baseline: 1.1394x; 1.0390x over previous
//
#include <hip/hip_runtime.h>

#define SPATIAL 16384
#define BATCH 8
#define CDIM 384
#define QVDIM 768
#define PDIM 192
#define NHEADS 8
#define HC 48

typedef __attribute__((ext_vector_type(8))) short short8;
typedef __attribute__((ext_vector_type(4))) float f32x4;
typedef __attribute__((ext_vector_type(4))) int i32x4;

__device__ __forceinline__ unsigned short f2bf(float f) {
  union { float f; unsigned u; } v; v.f = f;
  unsigned r = v.u + 0x7fffu + ((v.u >> 16) & 1u);
  return (unsigned short)(r >> 16);
}
__device__ __forceinline__ float bf2f(unsigned short h) {
  union { unsigned u; float f; } v; v.u = ((unsigned)h) << 16;
  return v.f;
}

// async global->LDS, 16B per lane; LDS dest is wave-uniform base + lane*16
__device__ __forceinline__ void gload16(const unsigned short* g, unsigned short* lds) {
  __builtin_amdgcn_global_load_lds(
      (const __attribute__((address_space(1))) void*)g,
      (__attribute__((address_space(3))) void*)lds,
      16, 0, 0);
}

// ================= device bodies (verbatim from r11 kernels) =================

__device__ __forceinline__ void w2bf_body(int bid, const float* __restrict__ in,
                                          unsigned short* __restrict__ out, int n) {
  int i = bid * 256 + threadIdx.x;
  if (i < n) out[i] = f2bf(in[i]);
}

__device__ __forceinline__ void transpose_body(int bid, const float* __restrict__ in,
                                               unsigned short* __restrict__ out, int C,
                                               float (*tile)[65]) {
  int st = bid % (SPATIAL / 64); bid /= (SPATIAL / 64);
  int ct = bid % (C / 64); int b = bid / (C / 64);
  int t = threadIdx.x;
  const float* ip = in + ((size_t)b * C + (size_t)ct * 64) * SPATIAL + (size_t)st * 64;
  int fx = t & 15, fy = t >> 4;
#pragma unroll
  for (int i = 0; i < 4; i++) {
    int r = fy + i * 16;
    f32x4 v = *(const f32x4*)(ip + (size_t)r * SPATIAL + fx * 4);
    tile[r][fx * 4 + 0] = v[0];
    tile[r][fx * 4 + 1] = v[1];
    tile[r][fx * 4 + 2] = v[2];
    tile[r][fx * 4 + 3] = v[3];
  }
  __syncthreads();
  unsigned short* op = out + ((size_t)b * SPATIAL + (size_t)st * 64) * C + (size_t)ct * 64;
  int cg = t & 7, sr = t >> 3;
#pragma unroll
  for (int i = 0; i < 2; i++) {
    int s = sr + i * 32;
    short8 o;
#pragma unroll
    for (int j = 0; j < 8; j++) o[j] = (short)f2bf(tile[cg * 8 + j][s]);
    *(short8*)(op + (size_t)s * C + cg * 8) = o;
  }
}

// r8/r11 GEMM body: BK=64 double-buffered, one barrier pair per K-tile (64 MFMA),
// stage j+2 after reads-done barrier, counted vmcnt(SL) never drains mid-loop.
template<int BM, bool OUT_BF16>
__device__ __forceinline__ void gemm_body(int lbid, int nwg,
    const unsigned short* __restrict__ A, const unsigned short* __restrict__ B,
    void* __restrict__ Cv, int M, int K, long strideA, unsigned short* lds)
{
  constexpr int MFR = BM / 32;          // m-frags per wave (8 or 4)
  constexpr int ARD = BM / 64;          // A staging rounds (4 or 2)
  constexpr int SL  = ARD + 4;          // stage loads per thread per K-tile
  constexpr int ASZ = BM * 64;          // A-tile elems
  constexpr int BUF = ASZ + 256 * 64;   // elems per buffer

  int bid = (lbid & 7) * (nwg >> 3) + (lbid >> 3);   // XCD chunk swizzle (nwg % 8 == 0)
  int mt = M / BM;
  int mb = bid % mt; bid /= mt;
  int nb = bid & 63; int b = bid >> 6;

  const unsigned short* Ab = A + (size_t)b * strideA + (size_t)mb * BM * K;
  const unsigned short* Bb = B + ((size_t)b * SPATIAL + (size_t)nb * 256) * K;

  int t = threadIdx.x;
  int lane = t & 63;
  int w = t >> 6;
  int wm = (w >> 2) * (BM / 2), wn = (w & 3) * 64;
  int lr = lane & 15, lg = lane >> 4;

  f32x4 acc[MFR][4];
#pragma unroll
  for (int i = 0; i < MFR; i++)
#pragma unroll
    for (int j = 0; j < 4; j++)
      acc[i][j] = (f32x4){0.f, 0.f, 0.f, 0.f};

  // staging: thread t -> row (t>>3) per 64-row round, k-slot (t&7)^(row&7)
  int arow = t >> 3;
  int aslot = (t & 7) ^ (arow & 7);
  const unsigned short* gA0 = Ab + (size_t)arow * K + aslot * 8;
  const unsigned short* gB0 = Bb + (size_t)arow * K + aslot * 8;

  auto STAGE = [&](int kt, int q) {
    int k0 = kt * 64;
    unsigned short* base = &lds[q * BUF];
#pragma unroll
    for (int r = 0; r < ARD; ++r)
      gload16(gA0 + (size_t)r * 64 * K + k0, base + r * 4096 + w * 512);
#pragma unroll
    for (int r = 0; r < 4; ++r)
      gload16(gB0 + (size_t)r * 64 * K + k0, base + ASZ + r * 4096 + w * 512);
  };

  int nt = K >> 6;                      // 6 or 3
  STAGE(0, 0);
  STAGE(1, 1);

  // fragment read slot per k-half (xor term is lr&7 for every frag row)
  int colr0 = ((0 * 4 + lg) ^ (lr & 7)) * 8;
  int colr1 = ((1 * 4 + lg) ^ (lr & 7)) * 8;

  for (int j = 0; j < nt; ++j) {
    if (j + 1 < nt) { asm volatile("s_waitcnt vmcnt(%0)" :: "n"(SL) : "memory"); }
    else            { asm volatile("s_waitcnt vmcnt(0)" ::: "memory"); }
    __builtin_amdgcn_s_barrier();            // (a) tile j published
    __builtin_amdgcn_sched_barrier(0);

    unsigned short* cb = &lds[(j & 1) * BUF];

    {  // k-half 0
      short8 af[MFR], bfv[4];
#pragma unroll
      for (int mi = 0; mi < MFR; ++mi)
        af[mi] = *(const short8*)(&cb[(wm + mi * 16 + lr) * 64 + colr0]);
#pragma unroll
      for (int ni = 0; ni < 4; ++ni)
        bfv[ni] = *(const short8*)(&cb[ASZ + (wn + ni * 16 + lr) * 64 + colr0]);
      __builtin_amdgcn_s_setprio(1);
#pragma unroll
      for (int mi = 0; mi < MFR; ++mi)
#pragma unroll
        for (int ni = 0; ni < 4; ++ni)
          acc[mi][ni] = __builtin_amdgcn_mfma_f32_16x16x32_bf16(af[mi], bfv[ni], acc[mi][ni], 0, 0, 0);
      __builtin_amdgcn_s_setprio(0);
    }
    __builtin_amdgcn_sched_barrier(0);       // keep halves separate (reg pressure)
    {  // k-half 1
      short8 af[MFR], bfv[4];
#pragma unroll
      for (int mi = 0; mi < MFR; ++mi)
        af[mi] = *(const short8*)(&cb[(wm + mi * 16 + lr) * 64 + colr1]);
#pragma unroll
      for (int ni = 0; ni < 4; ++ni)
        bfv[ni] = *(const short8*)(&cb[ASZ + (wn + ni * 16 + lr) * 64 + colr1]);
      __builtin_amdgcn_s_setprio(1);
#pragma unroll
      for (int mi = 0; mi < MFR; ++mi)
#pragma unroll
        for (int ni = 0; ni < 4; ++ni)
          acc[mi][ni] = __builtin_amdgcn_mfma_f32_16x16x32_bf16(af[mi], bfv[ni], acc[mi][ni], 0, 0, 0);
      __builtin_amdgcn_s_setprio(0);
    }
    __builtin_amdgcn_sched_barrier(0);
    __builtin_amdgcn_s_barrier();            // (b) all reads done: buffer free
    if (j + 2 < nt) STAGE(j + 2, j & 1);
  }

  size_t rbase = (size_t)mb * BM + wm + lg * 4;
  size_t cbase = (size_t)nb * 256 + wn + lr;
  if (OUT_BF16) {
    unsigned short* C = (unsigned short*)Cv + (size_t)b * M * SPATIAL;
#pragma unroll
    for (int mi = 0; mi < MFR; ++mi)
#pragma unroll
      for (int ni = 0; ni < 4; ++ni) {
        size_t r = rbase + mi * 16;
        size_t c = cbase + ni * 16;
#pragma unroll
        for (int jj = 0; jj < 4; ++jj)
          C[(r + jj) * SPATIAL + c] = f2bf(acc[mi][ni][jj]);
      }
  } else {
    float* C = (float*)Cv + (size_t)b * M * SPATIAL;
#pragma unroll
    for (int mi = 0; mi < MFR; ++mi)
#pragma unroll
      for (int ni = 0; ni < 4; ++ni) {
        size_t r = rbase + mi * 16;
        size_t c = cbase + ni * 16;
#pragma unroll
        for (int jj = 0; jj < 4; ++jj)
          C[(r + jj) * SPATIAL + c] = acc[mi][ni][jj];
      }
  }
}

// depthwise 3x3, vectorized, shfl halo (r11)
template<bool NORM>
__device__ __forceinline__ void dwconv_body(int bid, const unsigned short* __restrict__ in,
    const float* __restrict__ wdw, unsigned short* __restrict__ out,
    float* __restrict__ norm2, int C, int in_cstride, int chan_off)
{
  int yt = bid & 7; bid >>= 3;                        // 8 y-tiles of 16 rows
  int c = bid % C; int b = bid / C;
  const unsigned short* ip = in + ((size_t)b * in_cstride + chan_off + c) * SPATIAL;
  const float* wp = wdw + (size_t)(chan_off + c) * 9;
  float wr[9];
#pragma unroll
  for (int i = 0; i < 9; i++) wr[i] = wp[i];

  int t = threadIdx.x;
  int l = t & 63;                                     // lane
  int g = t & 15;                                     // x-group within row
  int ty = t >> 4, xs = g * 8;
  int y = yt * 16 + ty;

  float acc[8];
#pragma unroll
  for (int j = 0; j < 8; j++) acc[j] = 0.f;

  auto row = [&](int yy, float wa, float wb, float wc) {
    if ((unsigned)yy >= 128u) return;
    const unsigned short* rp = ip + yy * 128 + xs;
    short8 cv = *(const short8*)rp;
    float cf[8];
#pragma unroll
    for (int j = 0; j < 8; j++) cf[j] = bf2f((unsigned short)cv[j]);
    float lf = __shfl(cf[7], (l - 1) & 63, 64);
    float rt = __shfl(cf[0], (l + 1) & 63, 64);
    if (g == 0)  lf = 0.f;
    if (g == 15) rt = 0.f;
    acc[0] += wa * lf + wb * cf[0] + wc * cf[1];
#pragma unroll
    for (int j = 1; j < 7; j++) acc[j] += wa * cf[j - 1] + wb * cf[j] + wc * cf[j + 1];
    acc[7] += wa * cf[6] + wb * cf[7] + wc * rt;
  };
  row(y - 1, wr[0], wr[1], wr[2]);
  row(y,     wr[3], wr[4], wr[5]);
  row(y + 1, wr[6], wr[7], wr[8]);

  short8 o;
  float sq = 0.f;
#pragma unroll
  for (int j = 0; j < 8; j++) {
    o[j] = (short)f2bf(acc[j]);
    if (NORM) { float v = bf2f((unsigned short)o[j]); sq += v * v; }
  }
  *(short8*)(out + ((size_t)b * C + c) * SPATIAL + y * 128 + xs) = o;

  if (NORM) {
#pragma unroll
    for (int off = 32; off > 0; off >>= 1) sq += __shfl_down(sq, off, 64);
    __shared__ float red[4];
    if ((t & 63) == 0) red[t >> 6] = sq;
    __syncthreads();
    if (t == 0)
      atomicAdd(&norm2[(size_t)b * C + c], red[0] + red[1] + red[2] + red[3]);
  }
}

// depthwise 3x3 on v-half of qv, shfl halo, transposed out vT (r11)
__device__ __forceinline__ void dwt_body(int bid, const unsigned short* __restrict__ qv,
    const float* __restrict__ wdw, unsigned short* __restrict__ vT)
{
  __shared__ float tile[128][17];                     // [x][c-local]
  int y = bid & 127; bid >>= 7;
  int ct = bid % 24; int b = bid / 24;                // 24 tiles of 16 channels
  int t = threadIdx.x;
  int l = t & 63;
  int g = t & 15;
  int ci = t >> 4, xs = g * 8;
  int c = CDIM + ct * 16 + ci;
  const unsigned short* ip = qv + ((size_t)b * QVDIM + c) * SPATIAL;
  const float* wp = wdw + (size_t)c * 9;
  float wr[9];
#pragma unroll
  for (int i = 0; i < 9; i++) wr[i] = wp[i];

  float acc[8];
#pragma unroll
  for (int j = 0; j < 8; j++) acc[j] = 0.f;

  auto row = [&](int yy, float wa, float wb, float wc) {
    if ((unsigned)yy >= 128u) return;                 // y uniform per block: no divergence
    const unsigned short* rp = ip + yy * 128 + xs;
    short8 cv = *(const short8*)rp;
    float cf[8];
#pragma unroll
    for (int j = 0; j < 8; j++) cf[j] = bf2f((unsigned short)cv[j]);
    float lf = __shfl(cf[7], (l - 1) & 63, 64);
    float rt = __shfl(cf[0], (l + 1) & 63, 64);
    if (g == 0)  lf = 0.f;
    if (g == 15) rt = 0.f;
    acc[0] += wa * lf + wb * cf[0] + wc * cf[1];
#pragma unroll
    for (int j = 1; j < 7; j++) acc[j] += wa * cf[j - 1] + wb * cf[j] + wc * cf[j + 1];
    acc[7] += wa * cf[6] + wb * cf[7] + wc * rt;
  };
  row(y - 1, wr[0], wr[1], wr[2]);
  row(y,     wr[3], wr[4], wr[5]);
  row(y + 1, wr[6], wr[7], wr[8]);

#pragma unroll
  for (int j = 0; j < 8; j++) tile[xs + j][ci] = acc[j];
  __syncthreads();

  int xw = t >> 1, cg = t & 1;
  short8 o;
#pragma unroll
  for (int j = 0; j < 8; j++) o[j] = (short)f2bf(tile[xw][cg * 8 + j]);
  *(short8*)(vT + ((size_t)b * SPATIAL + (size_t)y * 128 + xw) * CDIM + ct * 16 + cg * 8) = o;
}

// ================= merged kernels =================

// prep: w2bf(w_qv) | w2bf(w_k) | transpose(x) | transpose(de)
#define PREP_N1 ((QVDIM * CDIM) / 256)
#define PREP_N2 ((CDIM * PDIM) / 256)
#define PREP_N3 (BATCH * (CDIM / 64) * (SPATIAL / 64))
#define PREP_N4 (BATCH * (PDIM / 64) * (SPATIAL / 64))
__global__ __launch_bounds__(256)
void k_prep(const float* __restrict__ w_qv, unsigned short* __restrict__ wqvb,
            const float* __restrict__ w_k, unsigned short* __restrict__ wkb,
            const float* __restrict__ x, unsigned short* __restrict__ xT,
            const float* __restrict__ de, unsigned short* __restrict__ deT)
{
  __shared__ float tile[64][65];
  int bid = blockIdx.x;
  if (bid < PREP_N1)                      w2bf_body(bid, w_qv, wqvb, QVDIM * CDIM);
  else if (bid < PREP_N1 + PREP_N2)       w2bf_body(bid - PREP_N1, w_k, wkb, CDIM * PDIM);
  else if (bid < PREP_N1 + PREP_N2 + PREP_N3)
    transpose_body(bid - PREP_N1 - PREP_N2, x, xT, CDIM, tile);
  else
    transpose_body(bid - PREP_N1 - PREP_N2 - PREP_N3, de, deT, PDIM, tile);
}

// GEMM1 (BM=256) + GEMM1b (BM=128) co-launched
#define G1_N  (BATCH * (QVDIM / 256) * (SPATIAL / 256))   // 1536
#define G1B_N (BATCH * (CDIM / 128) * (SPATIAL / 256))    // 1536
__global__ __launch_bounds__(512, 2)
void k_gemms(const unsigned short* __restrict__ A1, const unsigned short* __restrict__ B1,
             void* __restrict__ C1,
             const unsigned short* __restrict__ A2, const unsigned short* __restrict__ B2,
             void* __restrict__ C2)
{
  __shared__ unsigned short lds[2 * (256 * 64 + 256 * 64)];   // 131072 B (BM=256 size)
  int bid = blockIdx.x;
  if (bid < G1_N)
    gemm_body<256, true>(bid, G1_N, A1, B1, C1, QVDIM, CDIM, 0L, lds);
  else
    gemm_body<128, true>(bid - G1_N, G1B_N, A2, B2, C2, CDIM, PDIM, 0L, lds);
}

// all three depthwise convs co-launched
#define DW_NQ (BATCH * CDIM * 8)
#define DW_NT (BATCH * 24 * 128)
#define DW_NK (BATCH * CDIM * 8)
__global__ __launch_bounds__(256)
void k_dw(const unsigned short* __restrict__ qv, const unsigned short* __restrict__ kpre,
          const float* __restrict__ w_qvdw, const float* __restrict__ w_kdw,
          unsigned short* __restrict__ qdw, unsigned short* __restrict__ kdw,
          unsigned short* __restrict__ vT,
          float* __restrict__ n2q, float* __restrict__ n2k)
{
  int bid = blockIdx.x;
  if (bid < DW_NQ)
    dwconv_body<true>(bid, qv, w_qvdw, qdw, n2q, CDIM, QVDIM, 0);
  else if (bid < DW_NQ + DW_NT)
    dwt_body(bid - DW_NQ, qv, w_qvdw, vT);
  else
    dwconv_body<true>(bid - DW_NQ - DW_NT, kpre, w_kdw, kdw, n2k, CDIM, CDIM, 0);
}

// GEMM2 wrapper
__global__ __launch_bounds__(512, 2)
void k_gemm2(const unsigned short* __restrict__ A, const unsigned short* __restrict__ B,
             void* __restrict__ Cv)
{
  __shared__ unsigned short lds[2 * (128 * 64 + 256 * 64)];   // 98304 B
  gemm_body<128, false>(blockIdx.x, gridDim.x, A, B, Cv, CDIM, CDIM, (long)(CDIM * CDIM), lds);
}

// ---------------- raw attention logits: raw[b][h][c][d] += sum_s q[c,s]*k[d,s] ----------------
__global__ __launch_bounds__(256)
void k_logits(const unsigned short* __restrict__ qd, const unsigned short* __restrict__ kd,
              float* __restrict__ raw)
{
  int bid = blockIdx.x;
  int sp = bid & 15; bid >>= 4;
  int h = bid & 7; int b = bid >> 3;
  int lane = threadIdx.x & 63, wv = threadIdx.x >> 6;
  int lr = lane & 15, lg = lane >> 4;
  const unsigned short* qp = qd + ((size_t)b * CDIM + h * HC) * SPATIAL;
  const unsigned short* kp = kd + ((size_t)b * CDIM + h * HC) * SPATIAL;
  int s0 = sp * 1024 + wv * 256;
  f32x4 acc[3][3];
#pragma unroll
  for (int i = 0; i < 3; i++)
#pragma unroll
    for (int j = 0; j < 3; j++)
      acc[i][j] = (f32x4){0.f, 0.f, 0.f, 0.f};
  for (int ks = 0; ks < 256; ks += 32) {
    int off = s0 + ks + lg * 8;
    short8 qf[3], kf[3];
#pragma unroll
    for (int i = 0; i < 3; i++) {
      qf[i] = *(const short8*)(qp + (size_t)(i * 16 + lr) * SPATIAL + off);
      kf[i] = *(const short8*)(kp + (size_t)(i * 16 + lr) * SPATIAL + off);
    }
#pragma unroll
    for (int ci = 0; ci < 3; ci++)
#pragma unroll
      for (int di = 0; di < 3; di++)
        acc[ci][di] = __builtin_amdgcn_mfma_f32_16x16x32_bf16(qf[ci], kf[di], acc[ci][di], 0, 0, 0);
  }
  float* rp = raw + ((size_t)(b * NHEADS + h)) * HC * HC;
#pragma unroll
  for (int ci = 0; ci < 3; ci++)
#pragma unroll
    for (int di = 0; di < 3; di++)
#pragma unroll
      for (int j = 0; j < 4; j++)
        atomicAdd(&rp[(ci * 16 + lg * 4 + j) * HC + di * 16 + lr], acc[ci][di][j]);
}

// ---------------- scale by norms+temperature, softmax over d ----------------
__global__ void k_softmax(const float* __restrict__ raw, const float* __restrict__ n2q,
                          const float* __restrict__ n2k, const float* __restrict__ temp,
                          float* __restrict__ attn)
{
  int h = blockIdx.x & 7, b = blockIdx.x >> 3;
  int c = threadIdx.x;
  if (c >= HC) return;
  float tp = temp[h];
  float qn = fmaxf(sqrtf(n2q[b * CDIM + h * HC + c]), 1e-12f);
  const float* rp = raw + ((size_t)(b * NHEADS + h) * HC + c) * HC;
  float vals[HC];
  float mx = -1e30f;
#pragma unroll
  for (int d = 0; d < HC; d++) {
    float kn = fmaxf(sqrtf(n2k[b * CDIM + h * HC + d]), 1e-12f);
    float v = rp[d] * tp / (qn * kn);
    vals[d] = v;
    mx = fmaxf(mx, v);
  }
  float sum = 0.f;
#pragma unroll
  for (int d = 0; d < HC; d++) { vals[d] = expf(vals[d] - mx); sum += vals[d]; }
  float inv = 1.f / sum;
  float* ap = attn + ((size_t)(b * NHEADS + h) * HC + c) * HC;
#pragma unroll
  for (int d = 0; d < HC; d++) ap[d] = vals[d] * inv;
}

// ---------------- M[b][o][h*48+d] = sum_c wproj[o][h*48+c] * attn[b][h][c][d] ----------------
__global__ void k_mbuild(const float* __restrict__ attn, const float* __restrict__ wproj,
                         unsigned short* __restrict__ Mb)
{
  int o = blockIdx.x % CDIM, b = blockIdx.x / CDIM;
  int j = threadIdx.x;           // 0..383
  int h = j / HC, d = j % HC;
  const float* wp = wproj + (size_t)o * CDIM + h * HC;
  const float* ap = attn + (size_t)(b * NHEADS + h) * HC * HC + d;
  float s = 0.f;
#pragma unroll
  for (int cp = 0; cp < HC; cp++) s += wp[cp] * ap[cp * HC];
  Mb[((size_t)b * CDIM + o) * CDIM + j] = f2bf(s);
}

// ---------------- workspace layout (bytes) ----------------
static const size_t OFF_QV   = 0;            // qv bf16 [B][768][S]; later reused as k_dw
static const size_t OFF_KDW  = 0;            // alias: qv fully consumed before this is written
static const size_t OFF_XT   = 201326592;    // xT bf16 [B][S][384]; later q_dw [B][384][S]
static const size_t OFF_QDW  = 201326592;
static const size_t OFF_DET  = 301989888;    // deT bf16 [B][S][192]
static const size_t OFF_VT   = 301989888;    // vT bf16 [B][S][384] (alias over dead deT)
static const size_t OFF_KPRE = 402653184;    // k_pre bf16 [B][384][S]
static const size_t OFF_WQVB = 503316480;
static const size_t OFF_WKB  = 503906304;
static const size_t OFF_N2Q  = 504053760;
static const size_t OFF_N2K  = 504066048;
static const size_t OFF_RAW  = 504078336;
static const size_t OFF_ATTN = 504668160;
static const size_t OFF_MB   = 505257984;    // -> end ~484 MB

extern "C" void kernel_launch(void* const* d_in, const int* in_sizes, int n_in,
                              void* d_out, int out_size, void* d_ws, size_t ws_size,
                              hipStream_t stream) {
  const float* x      = (const float*)d_in[0];
  const float* de     = (const float*)d_in[1];
  const float* w_qv   = (const float*)d_in[2];
  const float* w_qvdw = (const float*)d_in[3];
  const float* w_k    = (const float*)d_in[4];
  const float* w_kdw  = (const float*)d_in[5];
  const float* w_proj = (const float*)d_in[6];
  const float* temp   = (const float*)d_in[7];

  char* ws = (char*)d_ws;
  unsigned short* qv    = (unsigned short*)(ws + OFF_QV);
  unsigned short* kdw   = (unsigned short*)(ws + OFF_KDW);
  unsigned short* xT    = (unsigned short*)(ws + OFF_XT);
  unsigned short* qdw   = (unsigned short*)(ws + OFF_QDW);
  unsigned short* deT   = (unsigned short*)(ws + OFF_DET);
  unsigned short* vT    = (unsigned short*)(ws + OFF_VT);
  unsigned short* kpre  = (unsigned short*)(ws + OFF_KPRE);
  unsigned short* wqvb  = (unsigned short*)(ws + OFF_WQVB);
  unsigned short* wkb   = (unsigned short*)(ws + OFF_WKB);
  float* n2q  = (float*)(ws + OFF_N2Q);
  float* n2k  = (float*)(ws + OFF_N2K);
  float* raw  = (float*)(ws + OFF_RAW);
  float* attn = (float*)(ws + OFF_ATTN);
  unsigned short* Mb = (unsigned short*)(ws + OFF_MB);

  hipMemsetAsync(ws + OFF_N2Q, 0, 12288 + 12288 + 589824, stream);

  // prep: weight casts + transposes (4 independent jobs, 1 dispatch)
  k_prep<<<dim3(PREP_N1 + PREP_N2 + PREP_N3 + PREP_N4), dim3(256), 0, stream>>>(
      w_qv, wqvb, w_k, wkb, x, xT, de, deT);

  // GEMM1 (qv = w_qv @ x) + GEMM1b (k_pre = w_k @ de), co-launched
  k_gemms<<<dim3(G1_N + G1B_N), dim3(512), 0, stream>>>(
      wqvb, xT, (void*)qv, wkb, deT, (void*)kpre);

  // all depthwise convs (3 independent jobs, 1 dispatch)
  k_dw<<<dim3(DW_NQ + DW_NT + DW_NK), dim3(256), 0, stream>>>(
      qv, kpre, w_qvdw, w_kdw, qdw, kdw, vT, n2q, n2k);

  // attention logits, softmax, combined projection matrix
  k_logits<<<dim3(BATCH * NHEADS * 16), dim3(256), 0, stream>>>(qdw, kdw, raw);
  k_softmax<<<dim3(BATCH * NHEADS), dim3(64), 0, stream>>>(raw, n2q, n2k, temp, attn);
  k_mbuild<<<dim3(BATCH * CDIM), dim3(CDIM), 0, stream>>>(attn, w_proj, Mb);

  // GEMM2: out = M[b] @ v  (M=384, K=384, BM=128), fp32 output
  k_gemm2<<<dim3(BATCH * (CDIM / 128) * (SPATIAL / 256)), dim3(512), 0, stream>>>(
      Mb, vT, d_out);
}

// Round 13
// 548.078 us; speedup vs baseline: 1.2056x; 1.0581x over previous
//
#include <hip/hip_runtime.h>

#define SPATIAL 16384
#define BATCH 8
#define CDIM 384
#define QVDIM 768
#define PDIM 192
#define NHEADS 8
#define HC 48

typedef __attribute__((ext_vector_type(8))) short short8;
typedef __attribute__((ext_vector_type(4))) float f32x4;
typedef __attribute__((ext_vector_type(4))) int i32x4;

__device__ __forceinline__ unsigned short f2bf(float f) {
  union { float f; unsigned u; } v; v.f = f;
  unsigned r = v.u + 0x7fffu + ((v.u >> 16) & 1u);
  return (unsigned short)(r >> 16);
}
__device__ __forceinline__ float bf2f(unsigned short h) {
  union { unsigned u; float f; } v; v.u = ((unsigned)h) << 16;
  return v.f;
}

// async global->LDS, 16B per lane; LDS dest is wave-uniform base + lane*16
__device__ __forceinline__ void gload16(const unsigned short* g, unsigned short* lds) {
  __builtin_amdgcn_global_load_lds(
      (const __attribute__((address_space(1))) void*)g,
      (__attribute__((address_space(3))) void*)lds,
      16, 0, 0);
}

// ================= device bodies =================

__device__ __forceinline__ void w2bf_body(int bid, const float* __restrict__ in,
                                          unsigned short* __restrict__ out, int n) {
  int i = bid * 256 + threadIdx.x;
  if (i < n) out[i] = f2bf(in[i]);
}

__device__ __forceinline__ void transpose_body(int bid, const float* __restrict__ in,
                                               unsigned short* __restrict__ out, int C,
                                               float (*tile)[65]) {
  int st = bid % (SPATIAL / 64); bid /= (SPATIAL / 64);
  int ct = bid % (C / 64); int b = bid / (C / 64);
  int t = threadIdx.x;
  const float* ip = in + ((size_t)b * C + (size_t)ct * 64) * SPATIAL + (size_t)st * 64;
  int fx = t & 15, fy = t >> 4;
#pragma unroll
  for (int i = 0; i < 4; i++) {
    int r = fy + i * 16;
    f32x4 v = *(const f32x4*)(ip + (size_t)r * SPATIAL + fx * 4);
    tile[r][fx * 4 + 0] = v[0];
    tile[r][fx * 4 + 1] = v[1];
    tile[r][fx * 4 + 2] = v[2];
    tile[r][fx * 4 + 3] = v[3];
  }
  __syncthreads();
  unsigned short* op = out + ((size_t)b * SPATIAL + (size_t)st * 64) * C + (size_t)ct * 64;
  int cg = t & 7, sr = t >> 3;
#pragma unroll
  for (int i = 0; i < 2; i++) {
    int s = sr + i * 32;
    short8 o;
#pragma unroll
    for (int j = 0; j < 8; j++) o[j] = (short)f2bf(tile[cg * 8 + j][s]);
    *(short8*)(op + (size_t)s * C + cg * 8) = o;
  }
}

// r8/r11 GEMM body: BK=64 double-buffered, one barrier pair per K-tile (64 MFMA),
// stage j+2 after reads-done barrier, counted vmcnt(SL) never drains mid-loop.
template<int BM, bool OUT_BF16>
__device__ __forceinline__ void gemm_body(int lbid, int nwg,
    const unsigned short* __restrict__ A, const unsigned short* __restrict__ B,
    void* __restrict__ Cv, int M, int K, long strideA, unsigned short* lds)
{
  constexpr int MFR = BM / 32;          // m-frags per wave (8 or 4)
  constexpr int ARD = BM / 64;          // A staging rounds (4 or 2)
  constexpr int SL  = ARD + 4;          // stage loads per thread per K-tile
  constexpr int ASZ = BM * 64;          // A-tile elems
  constexpr int BUF = ASZ + 256 * 64;   // elems per buffer

  int bid = (lbid & 7) * (nwg >> 3) + (lbid >> 3);   // XCD chunk swizzle (nwg % 8 == 0)
  int mt = M / BM;
  int mb = bid % mt; bid /= mt;
  int nb = bid & 63; int b = bid >> 6;

  const unsigned short* Ab = A + (size_t)b * strideA + (size_t)mb * BM * K;
  const unsigned short* Bb = B + ((size_t)b * SPATIAL + (size_t)nb * 256) * K;

  int t = threadIdx.x;
  int lane = t & 63;
  int w = t >> 6;
  int wm = (w >> 2) * (BM / 2), wn = (w & 3) * 64;
  int lr = lane & 15, lg = lane >> 4;

  f32x4 acc[MFR][4];
#pragma unroll
  for (int i = 0; i < MFR; i++)
#pragma unroll
    for (int j = 0; j < 4; j++)
      acc[i][j] = (f32x4){0.f, 0.f, 0.f, 0.f};

  // staging: thread t -> row (t>>3) per 64-row round, k-slot (t&7)^(row&7)
  int arow = t >> 3;
  int aslot = (t & 7) ^ (arow & 7);
  const unsigned short* gA0 = Ab + (size_t)arow * K + aslot * 8;
  const unsigned short* gB0 = Bb + (size_t)arow * K + aslot * 8;

  auto STAGE = [&](int kt, int q) {
    int k0 = kt * 64;
    unsigned short* base = &lds[q * BUF];
#pragma unroll
    for (int r = 0; r < ARD; ++r)
      gload16(gA0 + (size_t)r * 64 * K + k0, base + r * 4096 + w * 512);
#pragma unroll
    for (int r = 0; r < 4; ++r)
      gload16(gB0 + (size_t)r * 64 * K + k0, base + ASZ + r * 4096 + w * 512);
  };

  int nt = K >> 6;                      // 6 or 3
  STAGE(0, 0);
  STAGE(1, 1);

  // fragment read slot per k-half (xor term is lr&7 for every frag row)
  int colr0 = ((0 * 4 + lg) ^ (lr & 7)) * 8;
  int colr1 = ((1 * 4 + lg) ^ (lr & 7)) * 8;

  for (int j = 0; j < nt; ++j) {
    if (j + 1 < nt) { asm volatile("s_waitcnt vmcnt(%0)" :: "n"(SL) : "memory"); }
    else            { asm volatile("s_waitcnt vmcnt(0)" ::: "memory"); }
    __builtin_amdgcn_s_barrier();            // (a) tile j published
    __builtin_amdgcn_sched_barrier(0);

    unsigned short* cb = &lds[(j & 1) * BUF];

    {  // k-half 0
      short8 af[MFR], bfv[4];
#pragma unroll
      for (int mi = 0; mi < MFR; ++mi)
        af[mi] = *(const short8*)(&cb[(wm + mi * 16 + lr) * 64 + colr0]);
#pragma unroll
      for (int ni = 0; ni < 4; ++ni)
        bfv[ni] = *(const short8*)(&cb[ASZ + (wn + ni * 16 + lr) * 64 + colr0]);
      __builtin_amdgcn_s_setprio(1);
#pragma unroll
      for (int mi = 0; mi < MFR; ++mi)
#pragma unroll
        for (int ni = 0; ni < 4; ++ni)
          acc[mi][ni] = __builtin_amdgcn_mfma_f32_16x16x32_bf16(af[mi], bfv[ni], acc[mi][ni], 0, 0, 0);
      __builtin_amdgcn_s_setprio(0);
    }
    __builtin_amdgcn_sched_barrier(0);       // keep halves separate (reg pressure)
    {  // k-half 1
      short8 af[MFR], bfv[4];
#pragma unroll
      for (int mi = 0; mi < MFR; ++mi)
        af[mi] = *(const short8*)(&cb[(wm + mi * 16 + lr) * 64 + colr1]);
#pragma unroll
      for (int ni = 0; ni < 4; ++ni)
        bfv[ni] = *(const short8*)(&cb[ASZ + (wn + ni * 16 + lr) * 64 + colr1]);
      __builtin_amdgcn_s_setprio(1);
#pragma unroll
      for (int mi = 0; mi < MFR; ++mi)
#pragma unroll
        for (int ni = 0; ni < 4; ++ni)
          acc[mi][ni] = __builtin_amdgcn_mfma_f32_16x16x32_bf16(af[mi], bfv[ni], acc[mi][ni], 0, 0, 0);
      __builtin_amdgcn_s_setprio(0);
    }
    __builtin_amdgcn_sched_barrier(0);
    __builtin_amdgcn_s_barrier();            // (b) all reads done: buffer free
    if (j + 2 < nt) STAGE(j + 2, j & 1);
  }

  size_t rbase = (size_t)mb * BM + wm + lg * 4;
  size_t cbase = (size_t)nb * 256 + wn + lr;
  if (OUT_BF16) {
    unsigned short* C = (unsigned short*)Cv + (size_t)b * M * SPATIAL;
#pragma unroll
    for (int mi = 0; mi < MFR; ++mi)
#pragma unroll
      for (int ni = 0; ni < 4; ++ni) {
        size_t r = rbase + mi * 16;
        size_t c = cbase + ni * 16;
#pragma unroll
        for (int jj = 0; jj < 4; ++jj)
          C[(r + jj) * SPATIAL + c] = f2bf(acc[mi][ni][jj]);
      }
  } else {
    float* C = (float*)Cv + (size_t)b * M * SPATIAL;
#pragma unroll
    for (int mi = 0; mi < MFR; ++mi)
#pragma unroll
      for (int ni = 0; ni < 4; ++ni) {
        size_t r = rbase + mi * 16;
        size_t c = cbase + ni * 16;
#pragma unroll
        for (int jj = 0; jj < 4; ++jj)
          C[(r + jj) * SPATIAL + c] = acc[mi][ni][jj];
      }
  }
}

// ---- row-rolled depthwise 3x3 (8 y-rows x 8 px per thread, 3-row register window) ----
// block = (b, c): 256 threads = 16 y-strips x 16 x-groups -> whole channel.
// Loads/conversions per output: 0.156/1.25 (was 0.375/3). Norm: direct store.
template<bool NORM>
__device__ __forceinline__ void dwconv_body(int bid, const unsigned short* __restrict__ in,
    const float* __restrict__ wdw, unsigned short* __restrict__ out,
    float* __restrict__ norm2, int C, int in_cstride, int chan_off)
{
  int c = bid % C; int b = bid / C;
  const unsigned short* ip = in + ((size_t)b * in_cstride + chan_off + c) * SPATIAL;
  const float* wp = wdw + (size_t)(chan_off + c) * 9;
  float wr[9];
#pragma unroll
  for (int i = 0; i < 9; i++) wr[i] = wp[i];

  int t = threadIdx.x;
  int l = t & 63, g = t & 15;
  int y0 = (t >> 4) * 8;
  int xs = g * 8;
  unsigned short* op = out + ((size_t)b * C + c) * SPATIAL + y0 * 128 + xs;

  float rv[3][8], rl[3], rr[3];
  auto loadrow = [&](int yy, int s) {
    if ((unsigned)yy < 128u) {
      short8 cv = *(const short8*)(ip + yy * 128 + xs);
#pragma unroll
      for (int j = 0; j < 8; j++) rv[s][j] = bf2f((unsigned short)cv[j]);
    } else {
#pragma unroll
      for (int j = 0; j < 8; j++) rv[s][j] = 0.f;
    }
    float lf = __shfl(rv[s][7], (l - 1) & 63, 64);
    float rt = __shfl(rv[s][0], (l + 1) & 63, 64);
    rl[s] = (g == 0) ? 0.f : lf;
    rr[s] = (g == 15) ? 0.f : rt;
  };

  loadrow(y0 - 1, 0);
  loadrow(y0, 1);

  float sq = 0.f;
#pragma unroll
  for (int r = 0; r < 8; r++) {
    const int sp = r % 3, sc = (r + 1) % 3, sn = (r + 2) % 3;
    loadrow(y0 + r + 1, sn);
    float acc[8];
    acc[0] = wr[0]*rl[sp] + wr[1]*rv[sp][0] + wr[2]*rv[sp][1]
           + wr[3]*rl[sc] + wr[4]*rv[sc][0] + wr[5]*rv[sc][1]
           + wr[6]*rl[sn] + wr[7]*rv[sn][0] + wr[8]*rv[sn][1];
#pragma unroll
    for (int j = 1; j < 7; j++)
      acc[j] = wr[0]*rv[sp][j-1] + wr[1]*rv[sp][j] + wr[2]*rv[sp][j+1]
             + wr[3]*rv[sc][j-1] + wr[4]*rv[sc][j] + wr[5]*rv[sc][j+1]
             + wr[6]*rv[sn][j-1] + wr[7]*rv[sn][j] + wr[8]*rv[sn][j+1];
    acc[7] = wr[0]*rv[sp][6] + wr[1]*rv[sp][7] + wr[2]*rr[sp]
           + wr[3]*rv[sc][6] + wr[4]*rv[sc][7] + wr[5]*rr[sc]
           + wr[6]*rv[sn][6] + wr[7]*rv[sn][7] + wr[8]*rr[sn];
    short8 o;
#pragma unroll
    for (int j = 0; j < 8; j++) {
      o[j] = (short)f2bf(acc[j]);
      if (NORM) { float v = bf2f((unsigned short)o[j]); sq += v * v; }
    }
    *(short8*)(op + r * 128) = o;
  }

  if (NORM) {
#pragma unroll
    for (int off = 32; off > 0; off >>= 1) sq += __shfl_down(sq, off, 64);
    __shared__ float red[4];
    if (l == 0) red[t >> 6] = sq;
    __syncthreads();
    if (t == 0)
      norm2[(size_t)b * CDIM + c] = red[0] + red[1] + red[2] + red[3];
  }
}

// ---- row-rolled dwconv on v-half, transposed out vT [B][S][384] ----
// block = (b, ct of 16 chans, y-tile of 8 rows); per row: LDS transpose + coalesced write.
__device__ __forceinline__ void dwt_body(int bid, const unsigned short* __restrict__ qv,
    const float* __restrict__ wdw, unsigned short* __restrict__ vT)
{
  __shared__ float tile[128][17];
  int yt = bid & 15; bid >>= 4;          // 16 y-tiles of 8 rows
  int ct = bid % 24; int b = bid / 24;
  int t = threadIdx.x;
  int l = t & 63, g = t & 15;
  int ci = t >> 4;
  int xs = g * 8;
  int y0 = yt * 8;
  int c = CDIM + ct * 16 + ci;
  const unsigned short* ip = qv + ((size_t)b * QVDIM + c) * SPATIAL;
  const float* wp = wdw + (size_t)c * 9;
  float wr[9];
#pragma unroll
  for (int i = 0; i < 9; i++) wr[i] = wp[i];

  float rv[3][8], rl[3], rr[3];
  auto loadrow = [&](int yy, int s) {
    if ((unsigned)yy < 128u) {
      short8 cv = *(const short8*)(ip + yy * 128 + xs);
#pragma unroll
      for (int j = 0; j < 8; j++) rv[s][j] = bf2f((unsigned short)cv[j]);
    } else {
#pragma unroll
      for (int j = 0; j < 8; j++) rv[s][j] = 0.f;
    }
    float lf = __shfl(rv[s][7], (l - 1) & 63, 64);
    float rt = __shfl(rv[s][0], (l + 1) & 63, 64);
    rl[s] = (g == 0) ? 0.f : lf;
    rr[s] = (g == 15) ? 0.f : rt;
  };

  loadrow(y0 - 1, 0);
  loadrow(y0, 1);

  int xw = t >> 1, cg = t & 1;
#pragma unroll
  for (int r = 0; r < 8; r++) {
    const int sp = r % 3, sc = (r + 1) % 3, sn = (r + 2) % 3;
    loadrow(y0 + r + 1, sn);
    float acc[8];
    acc[0] = wr[0]*rl[sp] + wr[1]*rv[sp][0] + wr[2]*rv[sp][1]
           + wr[3]*rl[sc] + wr[4]*rv[sc][0] + wr[5]*rv[sc][1]
           + wr[6]*rl[sn] + wr[7]*rv[sn][0] + wr[8]*rv[sn][1];
#pragma unroll
    for (int j = 1; j < 7; j++)
      acc[j] = wr[0]*rv[sp][j-1] + wr[1]*rv[sp][j] + wr[2]*rv[sp][j+1]
             + wr[3]*rv[sc][j-1] + wr[4]*rv[sc][j] + wr[5]*rv[sc][j+1]
             + wr[6]*rv[sn][j-1] + wr[7]*rv[sn][j] + wr[8]*rv[sn][j+1];
    acc[7] = wr[0]*rv[sp][6] + wr[1]*rv[sp][7] + wr[2]*rr[sp]
           + wr[3]*rv[sc][6] + wr[4]*rv[sc][7] + wr[5]*rr[sc]
           + wr[6]*rv[sn][6] + wr[7]*rv[sn][7] + wr[8]*rr[sn];
#pragma unroll
    for (int j = 0; j < 8; j++) tile[xs + j][ci] = acc[j];
    __syncthreads();
    short8 o;
#pragma unroll
    for (int j = 0; j < 8; j++) o[j] = (short)f2bf(tile[xw][cg * 8 + j]);
    *(short8*)(vT + ((size_t)b * SPATIAL + (size_t)(y0 + r) * 128 + xw) * CDIM + ct * 16 + cg * 8) = o;
    __syncthreads();
  }
}

// ================= merged kernels =================

// prep: w2bf(w_qv) | w2bf(w_k) | transpose(x) | transpose(de)
#define PREP_N1 ((QVDIM * CDIM) / 256)
#define PREP_N2 ((CDIM * PDIM) / 256)
#define PREP_N3 (BATCH * (CDIM / 64) * (SPATIAL / 64))
#define PREP_N4 (BATCH * (PDIM / 64) * (SPATIAL / 64))
__global__ __launch_bounds__(256)
void k_prep(const float* __restrict__ w_qv, unsigned short* __restrict__ wqvb,
            const float* __restrict__ w_k, unsigned short* __restrict__ wkb,
            const float* __restrict__ x, unsigned short* __restrict__ xT,
            const float* __restrict__ de, unsigned short* __restrict__ deT)
{
  __shared__ float tile[64][65];
  int bid = blockIdx.x;
  if (bid < PREP_N1)                      w2bf_body(bid, w_qv, wqvb, QVDIM * CDIM);
  else if (bid < PREP_N1 + PREP_N2)       w2bf_body(bid - PREP_N1, w_k, wkb, CDIM * PDIM);
  else if (bid < PREP_N1 + PREP_N2 + PREP_N3)
    transpose_body(bid - PREP_N1 - PREP_N2, x, xT, CDIM, tile);
  else
    transpose_body(bid - PREP_N1 - PREP_N2 - PREP_N3, de, deT, PDIM, tile);
}

// GEMM1 (BM=256) + GEMM1b (BM=128) co-launched
#define G1_N  (BATCH * (QVDIM / 256) * (SPATIAL / 256))   // 1536
#define G1B_N (BATCH * (CDIM / 128) * (SPATIAL / 256))    // 1536
__global__ __launch_bounds__(512, 2)
void k_gemms(const unsigned short* __restrict__ A1, const unsigned short* __restrict__ B1,
             void* __restrict__ C1,
             const unsigned short* __restrict__ A2, const unsigned short* __restrict__ B2,
             void* __restrict__ C2)
{
  __shared__ unsigned short lds[2 * (256 * 64 + 256 * 64)];   // 131072 B (BM=256 size)
  int bid = blockIdx.x;
  if (bid < G1_N)
    gemm_body<256, true>(bid, G1_N, A1, B1, C1, QVDIM, CDIM, 0L, lds);
  else
    gemm_body<128, true>(bid - G1_N, G1B_N, A2, B2, C2, CDIM, PDIM, 0L, lds);
}

// all three depthwise convs co-launched (row-rolled)
#define DW_NQ (BATCH * CDIM)
#define DW_NT (BATCH * 24 * 16)
#define DW_NK (BATCH * CDIM)
__global__ __launch_bounds__(256)
void k_dw(const unsigned short* __restrict__ qv, const unsigned short* __restrict__ kpre,
          const float* __restrict__ w_qvdw, const float* __restrict__ w_kdw,
          unsigned short* __restrict__ qdw, unsigned short* __restrict__ kdw,
          unsigned short* __restrict__ vT,
          float* __restrict__ n2q, float* __restrict__ n2k)
{
  int bid = blockIdx.x;
  if (bid < DW_NQ)
    dwconv_body<true>(bid, qv, w_qvdw, qdw, n2q, CDIM, QVDIM, 0);
  else if (bid < DW_NQ + DW_NT)
    dwt_body(bid - DW_NQ, qv, w_qvdw, vT);
  else
    dwconv_body<true>(bid - DW_NQ - DW_NT, kpre, w_kdw, kdw, n2k, CDIM, CDIM, 0);
}

// GEMM2 wrapper
__global__ __launch_bounds__(512, 2)
void k_gemm2(const unsigned short* __restrict__ A, const unsigned short* __restrict__ B,
             void* __restrict__ Cv)
{
  __shared__ unsigned short lds[2 * (128 * 64 + 256 * 64)];   // 98304 B
  gemm_body<128, false>(blockIdx.x, gridDim.x, A, B, Cv, CDIM, CDIM, (long)(CDIM * CDIM), lds);
}

// ---------------- raw attention logits: raw[b][h][c][d] += sum_s q[c,s]*k[d,s] ----------------
__global__ __launch_bounds__(256)
void k_logits(const unsigned short* __restrict__ qd, const unsigned short* __restrict__ kd,
              float* __restrict__ raw)
{
  int bid = blockIdx.x;
  int sp = bid & 15; bid >>= 4;
  int h = bid & 7; int b = bid >> 3;
  int lane = threadIdx.x & 63, wv = threadIdx.x >> 6;
  int lr = lane & 15, lg = lane >> 4;
  const unsigned short* qp = qd + ((size_t)b * CDIM + h * HC) * SPATIAL;
  const unsigned short* kp = kd + ((size_t)b * CDIM + h * HC) * SPATIAL;
  int s0 = sp * 1024 + wv * 256;
  f32x4 acc[3][3];
#pragma unroll
  for (int i = 0; i < 3; i++)
#pragma unroll
    for (int j = 0; j < 3; j++)
      acc[i][j] = (f32x4){0.f, 0.f, 0.f, 0.f};
  for (int ks = 0; ks < 256; ks += 32) {
    int off = s0 + ks + lg * 8;
    short8 qf[3], kf[3];
#pragma unroll
    for (int i = 0; i < 3; i++) {
      qf[i] = *(const short8*)(qp + (size_t)(i * 16 + lr) * SPATIAL + off);
      kf[i] = *(const short8*)(kp + (size_t)(i * 16 + lr) * SPATIAL + off);
    }
#pragma unroll
    for (int ci = 0; ci < 3; ci++)
#pragma unroll
      for (int di = 0; di < 3; di++)
        acc[ci][di] = __builtin_amdgcn_mfma_f32_16x16x32_bf16(qf[ci], kf[di], acc[ci][di], 0, 0, 0);
  }
  float* rp = raw + ((size_t)(b * NHEADS + h)) * HC * HC;
#pragma unroll
  for (int ci = 0; ci < 3; ci++)
#pragma unroll
    for (int di = 0; di < 3; di++)
#pragma unroll
      for (int j = 0; j < 4; j++)
        atomicAdd(&rp[(ci * 16 + lg * 4 + j) * HC + di * 16 + lr], acc[ci][di][j]);
}

// ---------------- scale by norms+temperature, softmax over d ----------------
__global__ void k_softmax(const float* __restrict__ raw, const float* __restrict__ n2q,
                          const float* __restrict__ n2k, const float* __restrict__ temp,
                          float* __restrict__ attn)
{
  int h = blockIdx.x & 7, b = blockIdx.x >> 3;
  int c = threadIdx.x;
  if (c >= HC) return;
  float tp = temp[h];
  float qn = fmaxf(sqrtf(n2q[b * CDIM + h * HC + c]), 1e-12f);
  const float* rp = raw + ((size_t)(b * NHEADS + h) * HC + c) * HC;
  float vals[HC];
  float mx = -1e30f;
#pragma unroll
  for (int d = 0; d < HC; d++) {
    float kn = fmaxf(sqrtf(n2k[b * CDIM + h * HC + d]), 1e-12f);
    float v = rp[d] * tp / (qn * kn);
    vals[d] = v;
    mx = fmaxf(mx, v);
  }
  float sum = 0.f;
#pragma unroll
  for (int d = 0; d < HC; d++) { vals[d] = expf(vals[d] - mx); sum += vals[d]; }
  float inv = 1.f / sum;
  float* ap = attn + ((size_t)(b * NHEADS + h) * HC + c) * HC;
#pragma unroll
  for (int d = 0; d < HC; d++) ap[d] = vals[d] * inv;
}

// ---------------- M[b][o][h*48+d] = sum_c wproj[o][h*48+c] * attn[b][h][c][d] ----------------
__global__ void k_mbuild(const float* __restrict__ attn, const float* __restrict__ wproj,
                         unsigned short* __restrict__ Mb)
{
  int o = blockIdx.x % CDIM, b = blockIdx.x / CDIM;
  int j = threadIdx.x;           // 0..383
  int h = j / HC, d = j % HC;
  const float* wp = wproj + (size_t)o * CDIM + h * HC;
  const float* ap = attn + (size_t)(b * NHEADS + h) * HC * HC + d;
  float s = 0.f;
#pragma unroll
  for (int cp = 0; cp < HC; cp++) s += wp[cp] * ap[cp * HC];
  Mb[((size_t)b * CDIM + o) * CDIM + j] = f2bf(s);
}

// ---------------- workspace layout (bytes) ----------------
static const size_t OFF_QV   = 0;            // qv bf16 [B][768][S]; later reused as k_dw
static const size_t OFF_KDW  = 0;            // alias: qv fully consumed before this is written
static const size_t OFF_XT   = 201326592;    // xT bf16 [B][S][384]; later q_dw [B][384][S]
static const size_t OFF_QDW  = 201326592;
static const size_t OFF_DET  = 301989888;    // deT bf16 [B][S][192]
static const size_t OFF_VT   = 301989888;    // vT bf16 [B][S][384] (alias over dead deT)
static const size_t OFF_KPRE = 402653184;    // k_pre bf16 [B][384][S]
static const size_t OFF_WQVB = 503316480;
static const size_t OFF_WKB  = 503906304;
static const size_t OFF_N2Q  = 504053760;
static const size_t OFF_N2K  = 504066048;
static const size_t OFF_RAW  = 504078336;
static const size_t OFF_ATTN = 504668160;
static const size_t OFF_MB   = 505257984;    // -> end ~484 MB

extern "C" void kernel_launch(void* const* d_in, const int* in_sizes, int n_in,
                              void* d_out, int out_size, void* d_ws, size_t ws_size,
                              hipStream_t stream) {
  const float* x      = (const float*)d_in[0];
  const float* de     = (const float*)d_in[1];
  const float* w_qv   = (const float*)d_in[2];
  const float* w_qvdw = (const float*)d_in[3];
  const float* w_k    = (const float*)d_in[4];
  const float* w_kdw  = (const float*)d_in[5];
  const float* w_proj = (const float*)d_in[6];
  const float* temp   = (const float*)d_in[7];

  char* ws = (char*)d_ws;
  unsigned short* qv    = (unsigned short*)(ws + OFF_QV);
  unsigned short* kdw   = (unsigned short*)(ws + OFF_KDW);
  unsigned short* xT    = (unsigned short*)(ws + OFF_XT);
  unsigned short* qdw   = (unsigned short*)(ws + OFF_QDW);
  unsigned short* deT   = (unsigned short*)(ws + OFF_DET);
  unsigned short* vT    = (unsigned short*)(ws + OFF_VT);
  unsigned short* kpre  = (unsigned short*)(ws + OFF_KPRE);
  unsigned short* wqvb  = (unsigned short*)(ws + OFF_WQVB);
  unsigned short* wkb   = (unsigned short*)(ws + OFF_WKB);
  float* n2q  = (float*)(ws + OFF_N2Q);
  float* n2k  = (float*)(ws + OFF_N2K);
  float* raw  = (float*)(ws + OFF_RAW);
  float* attn = (float*)(ws + OFF_ATTN);
  unsigned short* Mb = (unsigned short*)(ws + OFF_MB);

  hipMemsetAsync(ws + OFF_N2Q, 0, 12288 + 12288 + 589824, stream);

  // prep: weight casts + transposes (4 independent jobs, 1 dispatch)
  k_prep<<<dim3(PREP_N1 + PREP_N2 + PREP_N3 + PREP_N4), dim3(256), 0, stream>>>(
      w_qv, wqvb, w_k, wkb, x, xT, de, deT);

  // GEMM1 (qv = w_qv @ x) + GEMM1b (k_pre = w_k @ de), co-launched
  k_gemms<<<dim3(G1_N + G1B_N), dim3(512), 0, stream>>>(
      wqvb, xT, (void*)qv, wkb, deT, (void*)kpre);

  // all depthwise convs (3 independent jobs, 1 dispatch, row-rolled)
  k_dw<<<dim3(DW_NQ + DW_NT + DW_NK), dim3(256), 0, stream>>>(
      qv, kpre, w_qvdw, w_kdw, qdw, kdw, vT, n2q, n2k);

  // attention logits, softmax, combined projection matrix
  k_logits<<<dim3(BATCH * NHEADS * 16), dim3(256), 0, stream>>>(qdw, kdw, raw);
  k_softmax<<<dim3(BATCH * NHEADS), dim3(64), 0, stream>>>(raw, n2q, n2k, temp, attn);
  k_mbuild<<<dim3(BATCH * CDIM), dim3(CDIM), 0, stream>>>(attn, w_proj, Mb);

  // GEMM2: out = M[b] @ v  (M=384, K=384, BM=128), fp32 output
  k_gemm2<<<dim3(BATCH * (CDIM / 128) * (SPATIAL / 256)), dim3(512), 0, stream>>>(
      Mb, vT, d_out);
}